// Round 1
// baseline (710.674 us; speedup 1.0000x reference)
//
#include <hip/hip_runtime.h>
#include <hip/hip_bf16.h>

typedef __attribute__((ext_vector_type(8))) __bf16 bf16x8;
typedef __attribute__((ext_vector_type(4))) float f32x4;

#define MFMA16(a, b, c) __builtin_amdgcn_mfma_f32_16x16x32_bf16((a), (b), (c), 0, 0, 0)

static __device__ __forceinline__ unsigned short f2bf(float f) {
    unsigned int x = __builtin_bit_cast(unsigned int, f);
    unsigned int r = (x + 0x7FFFu + ((x >> 16) & 1u)) >> 16;  // RNE, finite inputs
    return (unsigned short)r;
}

static __device__ __forceinline__ bf16x8 bf8_zero() {
    uint4 z = make_uint4(0, 0, 0, 0);
    return __builtin_bit_cast(bf16x8, z);
}

// ---------------- fp32 -> bf16 elementwise (x) ----------------
__global__ __launch_bounds__(256) void xconv(const float* __restrict__ X,
                                             unsigned short* __restrict__ Xb, int n) {
    int i = (blockIdx.x * 256 + threadIdx.x) * 4;
    if (i < n) {
        float4 f = *(const float4*)(X + i);
        ushort4 o;
        o.x = f2bf(f.x); o.y = f2bf(f.y); o.z = f2bf(f.z); o.w = f2bf(f.w);
        *(ushort4*)(Xb + i) = o;
    }
}

// ---------------- fp32 W[K][N] -> bf16 WT[N][K] ----------------
__global__ __launch_bounds__(256) void wconv(const float* __restrict__ W,
                                             unsigned short* __restrict__ WT, int K, int N) {
    __shared__ unsigned short tile[32][33];
    int n0 = blockIdx.x * 32, k0 = blockIdx.y * 32;
    int c = threadIdx.x & 31, r8 = threadIdx.x >> 5;  // r8: 0..7
#pragma unroll
    for (int it = 0; it < 4; ++it) {
        int r = r8 + it * 8;
        tile[r][c] = f2bf(W[(size_t)(k0 + r) * N + n0 + c]);
    }
    __syncthreads();
#pragma unroll
    for (int it = 0; it < 4; ++it) {
        int r = r8 + it * 8;
        WT[(size_t)(n0 + r) * K + k0 + c] = tile[c][r];
    }
}

// ---------------- bf16 GEMM: C[M][N] = A[M][K] @ BT[N][K]^T + bias, *scale ----------------
// 128x128 tile, BK=32, 4 waves each computing 64x64 (4x4 frags of 16x16x32 MFMA).
__global__ __launch_bounds__(256) void gemm_bt(const unsigned short* __restrict__ A,
                                               const unsigned short* __restrict__ BT,
                                               const float* __restrict__ bias,
                                               unsigned short* __restrict__ C,
                                               int M, int N, int K, float scale) {
    __shared__ __align__(16) unsigned short As[128 * 40];  // +8 pad per row
    __shared__ __align__(16) unsigned short Bs[128 * 40];
    int t = threadIdx.x, lane = t & 63, wid = t >> 6;
    int wr = wid >> 1, wc = wid & 1;
    int lrow = lane & 15, lkg = lane >> 4;
    int m0 = blockIdx.y * 128, n0 = blockIdx.x * 128;

    f32x4 acc[4][4];
#pragma unroll
    for (int mi = 0; mi < 4; ++mi)
#pragma unroll
        for (int ni = 0; ni < 4; ++ni) acc[mi][ni] = (f32x4){0.f, 0.f, 0.f, 0.f};

    const unsigned short* Abase = A + (size_t)m0 * K;
    const unsigned short* Bbase = BT + (size_t)n0 * K;
    int r = t >> 2, c = t & 3;  // staging: 64 rows x 4 chunks of 16B, x2 row-halves

    for (int k0 = 0; k0 < K; k0 += 32) {
        __syncthreads();
        uint4 a0 = *(const uint4*)(Abase + (size_t)r * K + k0 + c * 8);
        uint4 a1 = *(const uint4*)(Abase + (size_t)(r + 64) * K + k0 + c * 8);
        uint4 b0 = *(const uint4*)(Bbase + (size_t)r * K + k0 + c * 8);
        uint4 b1 = *(const uint4*)(Bbase + (size_t)(r + 64) * K + k0 + c * 8);
        *(uint4*)&As[r * 40 + c * 8] = a0;
        *(uint4*)&As[(r + 64) * 40 + c * 8] = a1;
        *(uint4*)&Bs[r * 40 + c * 8] = b0;
        *(uint4*)&Bs[(r + 64) * 40 + c * 8] = b1;
        __syncthreads();

        bf16x8 af[4], bv[4];
#pragma unroll
        for (int mi = 0; mi < 4; ++mi)
            af[mi] = *(const bf16x8*)&As[(wr * 64 + mi * 16 + lrow) * 40 + lkg * 8];
#pragma unroll
        for (int ni = 0; ni < 4; ++ni)
            bv[ni] = *(const bf16x8*)&Bs[(wc * 64 + ni * 16 + lrow) * 40 + lkg * 8];
#pragma unroll
        for (int mi = 0; mi < 4; ++mi)
#pragma unroll
            for (int ni = 0; ni < 4; ++ni) acc[mi][ni] = MFMA16(af[mi], bv[ni], acc[mi][ni]);
    }

#pragma unroll
    for (int ni = 0; ni < 4; ++ni) {
        int col = n0 + wc * 64 + ni * 16 + lrow;
        float bval = bias[col];
#pragma unroll
        for (int mi = 0; mi < 4; ++mi) {
            int row = m0 + wr * 64 + mi * 16 + lkg * 4;
#pragma unroll
            for (int i = 0; i < 4; ++i)
                C[(size_t)(row + i) * N + col] = f2bf((acc[mi][ni][i] + bval) * scale);
        }
    }
}

// ---------------- flash attention ----------------
// grid (S/64, H, B); block 256 = 4 waves x 16 q-rows. KV tiles of 64. Dh=40 padded to 64.
__global__ __launch_bounds__(256) void attn(const unsigned short* __restrict__ q,
                                            const unsigned short* __restrict__ k,
                                            const unsigned short* __restrict__ v,
                                            float* __restrict__ out) {
    const int S = 1024, D = 5120, Dh = 40;
    int b = blockIdx.z, h = blockIdx.y, qt = blockIdx.x;
    int t = threadIdx.x, lane = t & 63, wid = t >> 6;
    int lrow = lane & 15, lkg = lane >> 4;

    __shared__ __align__(16) unsigned short Ks[64 * 72];     // [key][d(pad 72)]
    __shared__ __align__(16) unsigned short Vs[64 * 72];     // transposed: [d][key(pad 72)]
    __shared__ __align__(16) unsigned short Ps[4][16 * 72];  // per-wave P [qrow][key]

    const size_t base = ((size_t)b * S) * D + (size_t)h * Dh;
    int q0 = qt * 64 + wid * 16;

    // Q fragments (A-operand): row = lane&15, d = k0 + lkg*8 + j; d>=40 zeroed
    bf16x8 qf0, qf1;
    {
        const unsigned short* qp = q + base + (size_t)(q0 + lrow) * D;
        qf0 = *(const bf16x8*)(qp + lkg * 8);
        qf1 = (lkg == 0) ? *(const bf16x8*)(qp + 32) : bf8_zero();
    }

    f32x4 acc[3];
#pragma unroll
    for (int nb = 0; nb < 3; ++nb) acc[nb] = (f32x4){0.f, 0.f, 0.f, 0.f};
    float mrun[4], lrun[4];
#pragma unroll
    for (int i = 0; i < 4; ++i) { mrun[i] = -INFINITY; lrun[i] = 0.f; }

    for (int kt = 0; kt < 16; ++kt) {
        __syncthreads();
        // stage K tile: [64 keys][64 d] (d>=40 zero)
#pragma unroll
        for (int it = 0; it < 2; ++it) {
            int idx = t + it * 256;
            int rr = idx >> 3, cc = idx & 7;
            uint4 val = make_uint4(0, 0, 0, 0);
            if (cc < 5) val = *(const uint4*)(k + base + (size_t)(kt * 64 + rr) * D + cc * 8);
            *(uint4*)&Ks[rr * 72 + cc * 8] = val;
        }
        // stage V transposed: Vs[d][key]; rows 40..47 zero, 48..63 never read
#pragma unroll
        for (int it = 0; it < 2; ++it) {
            int idx = t + it * 256;
            int rr = idx & 63, cc = idx >> 6;  // rr == lane -> conflict-benign scatter
            if (cc < 6) {
                uint4 val = make_uint4(0, 0, 0, 0);
                if (cc < 5) val = *(const uint4*)(v + base + (size_t)(kt * 64 + rr) * D + cc * 8);
                const unsigned short* pv = (const unsigned short*)&val;
#pragma unroll
                for (int j = 0; j < 8; ++j) Vs[(cc * 8 + j) * 72 + rr] = pv[j];
            }
        }
        __syncthreads();

        // QK^T: scores[qrow][key] (q pre-scaled by 1/sqrt(40))
        f32x4 sf[4];
#pragma unroll
        for (int nb = 0; nb < 4; ++nb) {
            sf[nb] = (f32x4){0.f, 0.f, 0.f, 0.f};
            bf16x8 kf0 = *(const bf16x8*)&Ks[(nb * 16 + lrow) * 72 + lkg * 8];
            bf16x8 kf1 = *(const bf16x8*)&Ks[(nb * 16 + lrow) * 72 + 32 + lkg * 8];
            sf[nb] = MFMA16(qf0, kf0, sf[nb]);
            sf[nb] = MFMA16(qf1, kf1, sf[nb]);
        }

        // online softmax (rows = lkg*4+i, reduce across 16 lanes)
        float tm[4], al[4], rs[4];
#pragma unroll
        for (int i = 0; i < 4; ++i)
            tm[i] = fmaxf(fmaxf(sf[0][i], sf[1][i]), fmaxf(sf[2][i], sf[3][i]));
#pragma unroll
        for (int d = 1; d < 16; d <<= 1)
#pragma unroll
            for (int i = 0; i < 4; ++i) tm[i] = fmaxf(tm[i], __shfl_xor(tm[i], d));
#pragma unroll
        for (int i = 0; i < 4; ++i) {
            float mn = fmaxf(mrun[i], tm[i]);
            al[i] = __expf(mrun[i] - mn);
            mrun[i] = mn;
            rs[i] = 0.f;
        }
#pragma unroll
        for (int nb = 0; nb < 4; ++nb)
#pragma unroll
            for (int i = 0; i < 4; ++i) {
                float p = __expf(sf[nb][i] - mrun[i]);
                rs[i] += p;
                Ps[wid][(lkg * 4 + i) * 72 + nb * 16 + lrow] = f2bf(p);
            }
#pragma unroll
        for (int d = 1; d < 16; d <<= 1)
#pragma unroll
            for (int i = 0; i < 4; ++i) rs[i] += __shfl_xor(rs[i], d);
#pragma unroll
        for (int i = 0; i < 4; ++i) lrun[i] = lrun[i] * al[i] + rs[i];
#pragma unroll
        for (int nb = 0; nb < 3; ++nb)
#pragma unroll
            for (int i = 0; i < 4; ++i) acc[nb][i] *= al[i];

        // PV: out[qrow][d] += P[qrow][key] * V[key][d]
#pragma unroll
        for (int kk = 0; kk < 2; ++kk) {
            bf16x8 pf = *(const bf16x8*)&Ps[wid][lrow * 72 + kk * 32 + lkg * 8];
#pragma unroll
            for (int nb = 0; nb < 3; ++nb) {
                bf16x8 vf = *(const bf16x8*)&Vs[(nb * 16 + lrow) * 72 + kk * 32 + lkg * 8];
                acc[nb] = MFMA16(pf, vf, acc[nb]);
            }
        }
    }

    // epilogue: divide by row sum, store d<40
#pragma unroll
    for (int i = 0; i < 4; ++i) {
        float inv = 1.0f / lrun[i];
        int s = q0 + lkg * 4 + i;
#pragma unroll
        for (int nb = 0; nb < 3; ++nb) {
            int d = nb * 16 + lrow;
            if (d < Dh) out[((size_t)(b * S + s)) * D + h * Dh + d] = acc[nb][i] * inv;
        }
    }
}

extern "C" void kernel_launch(void* const* d_in, const int* in_sizes, int n_in,
                              void* d_out, int out_size, void* d_ws, size_t ws_size,
                              hipStream_t stream) {
    const int M = 2048, D = 5120, L = 1536;
    const float* x  = (const float*)d_in[0];
    const float* Wq = (const float*)d_in[1];
    const float* bq = (const float*)d_in[2];
    const float* Wc = (const float*)d_in[3];
    const float* bc = (const float*)d_in[4];
    const float* Wk = (const float*)d_in[5];
    const float* bk = (const float*)d_in[6];
    const float* Wv = (const float*)d_in[7];
    const float* bv = (const float*)d_in[8];
    float* out = (float*)d_out;

    unsigned short* ws = (unsigned short*)d_ws;
    size_t off = 0;
    unsigned short* xb  = ws + off; off += (size_t)M * D;   // x bf16
    unsigned short* WqT = ws + off; off += (size_t)D * D;   // [N=D][K=D]
    unsigned short* WcT = ws + off; off += (size_t)L * D;   // [N=L][K=D]
    unsigned short* WkT = ws + off; off += (size_t)D * L;   // [N=D][K=L]
    unsigned short* WvT = ws + off; off += (size_t)D * L;
    unsigned short* kvb = ws + off; off += (size_t)M * L;
    unsigned short* qb  = ws + off; off += (size_t)M * D;
    unsigned short* kb  = ws + off; off += (size_t)M * D;
    unsigned short* vb  = ws + off; off += (size_t)M * D;

    xconv<<<(M * D) / 1024, 256, 0, stream>>>(x, xb, M * D);
    wconv<<<dim3(D / 32, D / 32), 256, 0, stream>>>(Wq, WqT, D, D);
    wconv<<<dim3(L / 32, D / 32), 256, 0, stream>>>(Wc, WcT, D, L);
    wconv<<<dim3(D / 32, L / 32), 256, 0, stream>>>(Wk, WkT, L, D);
    wconv<<<dim3(D / 32, L / 32), 256, 0, stream>>>(Wv, WvT, L, D);

    const float qscale = 0.15811388300841898f;  // 1/sqrt(40)
    gemm_bt<<<dim3(D / 128, M / 128), 256, 0, stream>>>(xb, WqT, bq, qb, M, D, D, qscale);
    gemm_bt<<<dim3(L / 128, M / 128), 256, 0, stream>>>(xb, WcT, bc, kvb, M, L, D, 1.0f);
    gemm_bt<<<dim3(D / 128, M / 128), 256, 0, stream>>>(kvb, WkT, bk, kb, M, D, L, 1.0f);
    gemm_bt<<<dim3(D / 128, M / 128), 256, 0, stream>>>(kvb, WvT, bv, vb, M, D, L, 1.0f);

    attn<<<dim3(1024 / 64, 128, 2), 256, 0, stream>>>(qb, kb, vb, out);
}

// Round 2
// 601.375 us; speedup vs baseline: 1.1817x; 1.1817x over previous
//
#include <hip/hip_runtime.h>
#include <hip/hip_bf16.h>

typedef __attribute__((ext_vector_type(8))) __bf16 bf16x8;
typedef __attribute__((ext_vector_type(4))) __bf16 bf16x4;
typedef __attribute__((ext_vector_type(4))) float f32x4;

#define MFMA16(a, b, c) __builtin_amdgcn_mfma_f32_16x16x32_bf16((a), (b), (c), 0, 0, 0)

#if __has_builtin(__builtin_amdgcn_exp2f)
#define EXP2F(x) __builtin_amdgcn_exp2f(x)
#else
#define EXP2F(x) exp2f(x)
#endif

#define GLDS16(g, l)                                                             \
    __builtin_amdgcn_global_load_lds((const __attribute__((address_space(1))) void*)(g), \
                                     (__attribute__((address_space(3))) void*)(l), 16, 0, 0)

static __device__ __forceinline__ unsigned short cvt_bf(float f) {
    return __builtin_bit_cast(unsigned short, (__bf16)f);
}

static __device__ __forceinline__ bf16x8 bf8_zero() {
    uint4 z = make_uint4(0, 0, 0, 0);
    return __builtin_bit_cast(bf16x8, z);
}

// ---------------- fp32 -> bf16 elementwise (x) ----------------
__global__ __launch_bounds__(256) void xconv(const float* __restrict__ X,
                                             unsigned short* __restrict__ Xb, int n) {
    int i = (blockIdx.x * 256 + threadIdx.x) * 4;
    if (i < n) {
        float4 f = *(const float4*)(X + i);
        ushort4 o;
        o.x = cvt_bf(f.x); o.y = cvt_bf(f.y); o.z = cvt_bf(f.z); o.w = cvt_bf(f.w);
        *(ushort4*)(Xb + i) = o;
    }
}

// ---------------- fp32 W[K][N] -> bf16 WT[N][K] ----------------
__global__ __launch_bounds__(256) void wconv(const float* __restrict__ W,
                                             unsigned short* __restrict__ WT, int K, int N) {
    __shared__ unsigned short tile[32][33];  // [k][n]
    int n0 = blockIdx.x * 32, k0 = blockIdx.y * 32;
    int c = threadIdx.x & 31, r8 = threadIdx.x >> 5;
#pragma unroll
    for (int it = 0; it < 4; ++it) {
        int r = r8 + it * 8;
        tile[r][c] = cvt_bf(W[(size_t)(k0 + r) * N + n0 + c]);
    }
    __syncthreads();
    int k2 = (threadIdx.x & 15) * 2, n8 = threadIdx.x >> 4;  // n8: 0..15
#pragma unroll
    for (int it = 0; it < 2; ++it) {
        int n = n8 + it * 16;
        ushort2 o;
        o.x = tile[k2][n];
        o.y = tile[k2 + 1][n];
        *(ushort2*)&WT[(size_t)(n0 + n) * K + k0 + k2] = o;
    }
}

// ---------------- bf16 GEMM (m97 structure): C = A @ BT^T + bias, *scale ----------------
// 128x128 tile, BK=32, global_load_lds width 16, linear LDS [128][32].
__global__ __launch_bounds__(256) void gemm_bt(const unsigned short* __restrict__ A, int lda,
                                               const unsigned short* __restrict__ BT,
                                               const float* __restrict__ bias0,
                                               const float* __restrict__ bias1, int nsplit,
                                               unsigned short* __restrict__ C, int ldc,
                                               int K, float s0, float s1) {
    __shared__ __align__(16) unsigned short As[128 * 32];
    __shared__ __align__(16) unsigned short Bs[128 * 32];
    int t = threadIdx.x, lane = t & 63, wid = t >> 6;
    int wr = wid >> 1, wc = wid & 1;
    int lrow = lane & 15, lkg = lane >> 4;
    int m0 = blockIdx.y * 128, n0 = blockIdx.x * 128;

    f32x4 acc[4][4];
#pragma unroll
    for (int mi = 0; mi < 4; ++mi)
#pragma unroll
        for (int ni = 0; ni < 4; ++ni) acc[mi][ni] = (f32x4){0.f, 0.f, 0.f, 0.f};

    // staging: lane L covers LDS bytes (wid*1024 + i*4096 + L*16) -> row wid*16+i*64+L/4, col (L&3)*8
    int srow = wid * 16 + (lane >> 2);
    int scol = (lane & 3) * 8;
    const unsigned short* Ag = A + (size_t)(m0 + srow) * lda + scol;
    const unsigned short* Bg = BT + (size_t)(n0 + srow) * K + scol;
    unsigned short* Al = As + wid * 512;  // wave-uniform LDS base (bytes: wid*1024)
    unsigned short* Bl = Bs + wid * 512;

    for (int k0 = 0; k0 < K; k0 += 32) {
        __syncthreads();
        GLDS16(Ag + k0, Al);
        GLDS16(Ag + (size_t)64 * lda + k0, Al + 2048);
        GLDS16(Bg + k0, Bl);
        GLDS16(Bg + (size_t)64 * K + k0, Bl + 2048);
        __syncthreads();

        bf16x8 af[4], bv[4];
#pragma unroll
        for (int mi = 0; mi < 4; ++mi)
            af[mi] = *(const bf16x8*)&As[(wr * 64 + mi * 16 + lrow) * 32 + lkg * 8];
#pragma unroll
        for (int ni = 0; ni < 4; ++ni)
            bv[ni] = *(const bf16x8*)&Bs[(wc * 64 + ni * 16 + lrow) * 32 + lkg * 8];
#pragma unroll
        for (int mi = 0; mi < 4; ++mi)
#pragma unroll
            for (int ni = 0; ni < 4; ++ni) acc[mi][ni] = MFMA16(af[mi], bv[ni], acc[mi][ni]);
    }

#pragma unroll
    for (int ni = 0; ni < 4; ++ni) {
        int col = n0 + wc * 64 + ni * 16 + lrow;
        float bval = (col < nsplit) ? bias0[col] : bias1[col - nsplit];
        float scl = (col < nsplit) ? s0 : s1;
#pragma unroll
        for (int mi = 0; mi < 4; ++mi) {
            int row = m0 + wr * 64 + mi * 16 + lkg * 4;
#pragma unroll
            for (int i = 0; i < 4; ++i)
                C[(size_t)(row + i) * ldc + col] = cvt_bf((acc[mi][ni][i] + bval) * scl);
        }
    }
}

// ---------------- flash attention (swapped QK^T, exp2, packed P) ----------------
// grid (S/64, H, B); block 256 = 4 waves x 16 q-rows. KV tiles of 64. Dh=40 padded to 64.
// Scores arrive in log2 units (log2(e)/sqrt(40) folded into q).
__global__ __launch_bounds__(256) void attn(const unsigned short* __restrict__ q, int ldq,
                                            const unsigned short* __restrict__ k, int ldk,
                                            const unsigned short* __restrict__ v, int ldv,
                                            float* __restrict__ out) {
    const int S = 1024, D = 5120, Dh = 40;
    int b = blockIdx.z, h = blockIdx.y, qt = blockIdx.x;
    int t = threadIdx.x, lane = t & 63, wid = t >> 6;
    int lrow = lane & 15, lkg = lane >> 4;

    __shared__ __align__(16) unsigned short Ks[64 * 72];     // [key][d(pad 72)]
    __shared__ __align__(16) unsigned short Vs[64 * 72];     // transposed: [d][key(pad 72)]
    __shared__ __align__(16) unsigned short Ps[4][16 * 72];  // per-wave P [qrow][key(pad 72)]

    const size_t qbase = ((size_t)b * S) * ldq + (size_t)h * Dh;
    const size_t kbase = ((size_t)b * S) * ldk + (size_t)h * Dh;
    const size_t vbase = ((size_t)b * S) * ldv + (size_t)h * Dh;
    int q0 = qt * 64 + wid * 16;

    // Q fragment (B-operand): col = lane&15 = qrow, k-dim d = lkg*8+j; d>=40 zeroed
    bf16x8 qf0, qf1;
    {
        const unsigned short* qp = q + qbase + (size_t)(q0 + lrow) * ldq;
        qf0 = *(const bf16x8*)(qp + lkg * 8);
        qf1 = (lkg == 0) ? *(const bf16x8*)(qp + 32) : bf8_zero();
    }

    f32x4 acc[3];
#pragma unroll
    for (int nb = 0; nb < 3; ++nb) acc[nb] = (f32x4){0.f, 0.f, 0.f, 0.f};
    float mrun = -INFINITY, lrun = 0.f;  // stats for q-row = lrow (this lane's column)

    for (int kt = 0; kt < 16; ++kt) {
        __syncthreads();
        // stage K tile: [64 keys][64 d] (d>=40 zero)
#pragma unroll
        for (int it = 0; it < 2; ++it) {
            int idx = t + it * 256;
            int rr = idx >> 3, cc = idx & 7;
            uint4 val = make_uint4(0, 0, 0, 0);
            if (cc < 5) val = *(const uint4*)(k + kbase + (size_t)(kt * 64 + rr) * ldk + cc * 8);
            *(uint4*)&Ks[rr * 72 + cc * 8] = val;
        }
        // stage V transposed: Vs[d][key]; rows 40..47 zero
#pragma unroll
        for (int it = 0; it < 2; ++it) {
            int idx = t + it * 256;
            int rr = idx & 63, cc = idx >> 6;
            if (cc < 6) {
                uint4 val = make_uint4(0, 0, 0, 0);
                if (cc < 5) val = *(const uint4*)(v + vbase + (size_t)(kt * 64 + rr) * ldv + cc * 8);
                const unsigned short* pv = (const unsigned short*)&val;
#pragma unroll
                for (int j = 0; j < 8; ++j) Vs[(cc * 8 + j) * 72 + rr] = pv[j];
            }
        }
        __syncthreads();

        // QK^T swapped: sf[nb][i] = S^T[key = nb*16 + lkg*4 + i][qrow = lrow]
        f32x4 sf[4];
#pragma unroll
        for (int nb = 0; nb < 4; ++nb) {
            sf[nb] = (f32x4){0.f, 0.f, 0.f, 0.f};
            bf16x8 kf0 = *(const bf16x8*)&Ks[(nb * 16 + lrow) * 72 + lkg * 8];
            bf16x8 kf1 = *(const bf16x8*)&Ks[(nb * 16 + lrow) * 72 + 32 + lkg * 8];
            sf[nb] = MFMA16(kf0, qf0, sf[nb]);
            sf[nb] = MFMA16(kf1, qf1, sf[nb]);
        }

        // online softmax for column lrow: 16 local values + lanes lrow+{16,32,48}
        float tm = sf[0][0];
#pragma unroll
        for (int nb = 0; nb < 4; ++nb)
#pragma unroll
            for (int i = 0; i < 4; ++i) tm = fmaxf(tm, sf[nb][i]);
        tm = fmaxf(tm, __shfl_xor(tm, 16));
        tm = fmaxf(tm, __shfl_xor(tm, 32));
        float mn = fmaxf(mrun, tm);
        float al = EXP2F(mrun - mn);
        mrun = mn;
        float rs = 0.f;
#pragma unroll
        for (int nb = 0; nb < 4; ++nb) {
            bf16x4 pk;
#pragma unroll
            for (int i = 0; i < 4; ++i) {
                float p = EXP2F(sf[nb][i] - mn);
                rs += p;
                pk[i] = (__bf16)p;
            }
            *(bf16x4*)&Ps[wid][lrow * 72 + nb * 16 + lkg * 4] = pk;
        }
        rs += __shfl_xor(rs, 16);
        rs += __shfl_xor(rs, 32);
        lrun = lrun * al + rs;

        // rescale acc (acc rows are q-rows lkg*4+i; fetch al from the lane owning that row)
        float alr[4];
#pragma unroll
        for (int i = 0; i < 4; ++i) alr[i] = __shfl(al, lkg * 4 + i);
#pragma unroll
        for (int nb = 0; nb < 3; ++nb)
#pragma unroll
            for (int i = 0; i < 4; ++i) acc[nb][i] *= alr[i];

        // PV: out[qrow][d] += P[qrow][key] * V^T[d][key]
#pragma unroll
        for (int kk = 0; kk < 2; ++kk) {
            bf16x8 pf = *(const bf16x8*)&Ps[wid][lrow * 72 + kk * 32 + lkg * 8];
#pragma unroll
            for (int nb = 0; nb < 3; ++nb) {
                bf16x8 vf = *(const bf16x8*)&Vs[(nb * 16 + lrow) * 72 + kk * 32 + lkg * 8];
                acc[nb] = MFMA16(pf, vf, acc[nb]);
            }
        }
    }

    // epilogue: divide by row sum (held by lane lkg*4+i), store d<40
    float lr[4];
#pragma unroll
    for (int i = 0; i < 4; ++i) lr[i] = __shfl(lrun, lkg * 4 + i);
#pragma unroll
    for (int i = 0; i < 4; ++i) {
        float inv = 1.0f / lr[i];
        int s = q0 + lkg * 4 + i;
#pragma unroll
        for (int nb = 0; nb < 3; ++nb) {
            int d = nb * 16 + lrow;
            if (d < Dh) out[((size_t)(b * S + s)) * D + h * Dh + d] = acc[nb][i] * inv;
        }
    }
}

extern "C" void kernel_launch(void* const* d_in, const int* in_sizes, int n_in,
                              void* d_out, int out_size, void* d_ws, size_t ws_size,
                              hipStream_t stream) {
    const int M = 2048, D = 5120, L = 1536, NQ = D + L /*6656*/, NKV = 2 * D /*10240*/;
    const float* x  = (const float*)d_in[0];
    const float* Wq = (const float*)d_in[1];
    const float* bq = (const float*)d_in[2];
    const float* Wc = (const float*)d_in[3];
    const float* bc = (const float*)d_in[4];
    const float* Wk = (const float*)d_in[5];
    const float* bk = (const float*)d_in[6];
    const float* Wv = (const float*)d_in[7];
    const float* bv = (const float*)d_in[8];
    float* out = (float*)d_out;

    unsigned short* ws = (unsigned short*)d_ws;
    size_t off = 0;
    unsigned short* xb    = ws + off; off += (size_t)M * D;    // x bf16
    unsigned short* WqcT  = ws + off; off += (size_t)NQ * D;   // [Wq|Wc]^T : [6656][5120]
    unsigned short* WkvT  = ws + off; off += (size_t)NKV * L;  // [Wk|Wv]^T : [10240][1536]
    unsigned short* qkvb  = ws + off; off += (size_t)M * NQ;   // [q | kv_latent]
    unsigned short* kvout = ws + off; off += (size_t)M * NKV;  // [k | v]

    xconv<<<(M * D) / 1024, 256, 0, stream>>>(x, xb, M * D);
    wconv<<<dim3(D / 32, D / 32), 256, 0, stream>>>(Wq, WqcT, D, D);
    wconv<<<dim3(L / 32, D / 32), 256, 0, stream>>>(Wc, WqcT + (size_t)D * D, D, L);
    wconv<<<dim3(D / 32, L / 32), 256, 0, stream>>>(Wk, WkvT, L, D);
    wconv<<<dim3(D / 32, L / 32), 256, 0, stream>>>(Wv, WkvT + (size_t)D * L, L, D);

    // log2(e)/sqrt(40): scores come out in log2 units for exp2-based softmax
    const float qscale = 1.4426950408889634f / 6.324555320336759f;

    // GEMM1: [q | kv_latent] = x @ [Wq | Wc] ; q pre-scaled
    gemm_bt<<<dim3(NQ / 128, M / 128), 256, 0, stream>>>(xb, D, WqcT, bq, bc, D, qkvb, NQ,
                                                         D, qscale, 1.0f);
    // GEMM2: [k | v] = kv_latent @ [Wk | Wv]
    gemm_bt<<<dim3(NKV / 128, M / 128), 256, 0, stream>>>(qkvb + D, NQ, WkvT, bk, bv, D,
                                                          kvout, NKV, L, 1.0f, 1.0f);

    attn<<<dim3(1024 / 64, 128, 2), 256, 0, stream>>>(qkvb, NQ, kvout, NKV, kvout + D, NKV, out);
}

// Round 3
// 553.877 us; speedup vs baseline: 1.2831x; 1.0858x over previous
//
#include <hip/hip_runtime.h>
#include <hip/hip_bf16.h>

typedef __attribute__((ext_vector_type(8))) __bf16 bf16x8;
typedef __attribute__((ext_vector_type(4))) __bf16 bf16x4;
typedef __attribute__((ext_vector_type(4))) float f32x4;

#define MFMA16(a, b, c) __builtin_amdgcn_mfma_f32_16x16x32_bf16((a), (b), (c), 0, 0, 0)

#if __has_builtin(__builtin_amdgcn_exp2f)
#define EXP2F(x) __builtin_amdgcn_exp2f(x)
#else
#define EXP2F(x) exp2f(x)
#endif

#define GLDS16(g, l)                                                             \
    __builtin_amdgcn_global_load_lds((const __attribute__((address_space(1))) void*)(g), \
                                     (__attribute__((address_space(3))) void*)(l), 16, 0, 0)

// Raw barrier with compiler-level memory fences on both sides: prevents the
// optimizer from hoisting/sinking LDS reads or stage-issues across it (raw
// s_barrier intrinsic is not an IR memory fence).
#define BARRIER()                          \
    do {                                   \
        asm volatile("" ::: "memory");     \
        __builtin_amdgcn_s_barrier();      \
        asm volatile("" ::: "memory");     \
    } while (0)

#define WAIT_LGKM0() asm volatile("s_waitcnt lgkmcnt(0)" ::: "memory")
#define VM6 asm volatile("s_waitcnt vmcnt(6)" ::: "memory")
#define VM0 asm volatile("s_waitcnt vmcnt(0)" ::: "memory")
#define VMNONE ((void)0)
#define KEEP(x) x
#define DROP(x)

static __device__ __forceinline__ unsigned short cvt_bf(float f) {
    return __builtin_bit_cast(unsigned short, (__bf16)f);
}

static __device__ __forceinline__ bf16x8 bf8_zero() {
    uint4 z = make_uint4(0, 0, 0, 0);
    return __builtin_bit_cast(bf16x8, z);
}

// ---------------- fp32 -> bf16 elementwise (x) ----------------
__global__ __launch_bounds__(256) void xconv(const float* __restrict__ X,
                                             unsigned short* __restrict__ Xb, int n) {
    int i = (blockIdx.x * 256 + threadIdx.x) * 4;
    if (i < n) {
        float4 f = *(const float4*)(X + i);
        ushort4 o;
        o.x = cvt_bf(f.x); o.y = cvt_bf(f.y); o.z = cvt_bf(f.z); o.w = cvt_bf(f.w);
        *(ushort4*)(Xb + i) = o;
    }
}

// ---------------- fp32 W[K][N] -> bf16 WT[N][K] ----------------
__global__ __launch_bounds__(256) void wconv(const float* __restrict__ W,
                                             unsigned short* __restrict__ WT, int K, int N) {
    __shared__ unsigned short tile[32][33];  // [k][n]
    int n0 = blockIdx.x * 32, k0 = blockIdx.y * 32;
    int c = threadIdx.x & 31, r8 = threadIdx.x >> 5;
#pragma unroll
    for (int it = 0; it < 4; ++it) {
        int r = r8 + it * 8;
        tile[r][c] = cvt_bf(W[(size_t)(k0 + r) * N + n0 + c]);
    }
    __syncthreads();
    int k2 = (threadIdx.x & 15) * 2, n8 = threadIdx.x >> 4;
#pragma unroll
    for (int it = 0; it < 2; ++it) {
        int n = n8 + it * 16;
        ushort2 o;
        o.x = tile[k2][n];
        o.y = tile[k2 + 1][n];
        *(ushort2*)&WT[(size_t)(n0 + n) * K + k0 + k2] = o;
    }
}

// ================= 256x256 8-phase bf16 GEMM (T1+T2+T3+T4+T5) =================
// C[M][N] = A[M][K] @ BT[N][K]^T + bias, *scale.  BM=BN=256, BK=64, 512 thr (2Mx4N waves).
// LDS: A/B double-buffered 2x32KB each = 128KB. Quadrant-remapped rows so each
// 16KB half-region is consumed by exactly the phases that allow mid-tile overwrite:
//   A slot-row R = swap(bits6,7) of logical row;  B slot-row R = q<<7|wn<<5|lo.
// st_16x32 swizzle: phys_byte = lin_byte ^ ((lin_byte>>9 &1)<<5), applied on the
// global SOURCE at staging (gload_lds dest must stay linear) and on ds_read addrs.

#define STAGE_A(S, H, KT)                                                              \
    do {                                                                               \
        GLDS16(aS[H][0] + (size_t)(KT) * 64, &Abuf[S][(H) * 8192 + wid * 512]);        \
        GLDS16(aS[H][1] + (size_t)(KT) * 64, &Abuf[S][(H) * 8192 + 4096 + wid * 512]); \
    } while (0)
#define STAGE_B(S, H, KT)                                                              \
    do {                                                                               \
        GLDS16(bS[H][0] + (size_t)(KT) * 64, &Bbuf[S][(H) * 8192 + wid * 512]);        \
        GLDS16(bS[H][1] + (size_t)(KT) * 64, &Bbuf[S][(H) * 8192 + 4096 + wid * 512]); \
    } while (0)

#define LDA_HALF(S, QM)                                                                 \
    do {                                                                                \
        _Pragma("unroll") for (int mi = 0; mi < 4; ++mi)                                \
            _Pragma("unroll") for (int kh = 0; kh < 2; ++kh)                            \
                af[mi][kh] = *(const bf16x8*)&Abuf[S][aoff + (QM) * 8192 + mi * 1024 + kh * 32]; \
    } while (0)
#define LDB_HALF(S, QN, BF)                                                             \
    do {                                                                                \
        _Pragma("unroll") for (int ni = 0; ni < 2; ++ni)                                \
            _Pragma("unroll") for (int kh = 0; kh < 2; ++kh)                            \
                BF[ni][kh] = *(const bf16x8*)&Bbuf[S][boff + (QN) * 8192 + ni * 1024 + kh * 32]; \
    } while (0)

#define MMAQ(QM, QN, BF)                                                                \
    do {                                                                                \
        _Pragma("unroll") for (int mi = 0; mi < 4; ++mi)                                \
            _Pragma("unroll") for (int ni = 0; ni < 2; ++ni)                            \
                _Pragma("unroll") for (int kh = 0; kh < 2; ++kh)                        \
                    acc[(QM) * 4 + mi][(QN) * 2 + ni] =                                 \
                        MFMA16(af[mi][kh], BF[ni][kh], acc[(QM) * 4 + mi][(QN) * 2 + ni]); \
    } while (0)

// One K-tile = 4 phases. Stage plan (steady state, tile T in slot S):
//  ph1: read A0,B0 | stage (T+1).B0 -> S^1 ; ph2: read B1 | stage (T+2).A0 -> S
//  ph3: read A1    | stage (T+2).B1 -> S   ; ph4: read B0 | stage (T+2).A1 -> S, vmcnt(6)
#define KTILE(S, T, STG1, STG234, VMOP)             \
    {                                               \
        const int s_ = (S);                         \
        LDA_HALF(s_, 0);                            \
        LDB_HALF(s_, 0, bf0);                       \
        STG1(STAGE_B(s_ ^ 1, 0, (T) + 1);)          \
        asm volatile("s_waitcnt lgkmcnt(8)" ::: "memory"); \
        BARRIER();                                  \
        WAIT_LGKM0();                               \
        __builtin_amdgcn_s_setprio(1);              \
        MMAQ(0, 0, bf0);                            \
        __builtin_amdgcn_s_setprio(0);              \
        BARRIER();                                  \
        LDB_HALF(s_, 1, bf1);                       \
        STG234(STAGE_A(s_, 0, (T) + 2);)            \
        BARRIER();                                  \
        WAIT_LGKM0();                               \
        __builtin_amdgcn_s_setprio(1);              \
        MMAQ(0, 1, bf1);                            \
        __builtin_amdgcn_s_setprio(0);              \
        BARRIER();                                  \
        LDA_HALF(s_, 1);                            \
        STG234(STAGE_B(s_, 1, (T) + 2);)            \
        BARRIER();                                  \
        WAIT_LGKM0();                               \
        __builtin_amdgcn_s_setprio(1);              \
        MMAQ(1, 1, bf1);                            \
        __builtin_amdgcn_s_setprio(0);              \
        BARRIER();                                  \
        LDB_HALF(s_, 0, bf0);                       \
        STG234(STAGE_A(s_, 1, (T) + 2);)            \
        VMOP;                                       \
        BARRIER();                                  \
        WAIT_LGKM0();                               \
        __builtin_amdgcn_s_setprio(1);              \
        MMAQ(1, 0, bf0);                            \
        __builtin_amdgcn_s_setprio(0);              \
        BARRIER();                                  \
    }

__global__ __launch_bounds__(512, 2) void gemm256(const unsigned short* __restrict__ A, int lda,
                                                  const unsigned short* __restrict__ BT, int ldb,
                                                  const float* __restrict__ bias0,
                                                  const float* __restrict__ bias1, int nsplit,
                                                  unsigned short* __restrict__ C, int ldc,
                                                  int K, float s0, float s1, int gx) {
    __shared__ __align__(16) unsigned short Abuf[2][16384];  // 2 x 32KB
    __shared__ __align__(16) unsigned short Bbuf[2][16384];

    // XCD-aware bijective swizzle (gridDim.x % 8 == 0 by construction)
    int nwg = gridDim.x, orig = blockIdx.x;
    int cpx = nwg >> 3;
    int wgid = (orig & 7) * cpx + (orig >> 3);
    int tm = wgid / gx, tn = wgid % gx;
    int m0 = tm * 256, n0 = tn * 256;

    int tid = threadIdx.x, lane = tid & 63, wid = tid >> 6;
    int wm = wid >> 2, wn = wid & 3;
    int lrow = lane & 15, lkg = lane >> 4;

    // ---- staging source addresses (pre-swizzled global, linear LDS dest) ----
    int t5 = tid >> 3;                                  // 6 bits
    int colb = ((tid & 7) * 16) ^ (tid & 32);           // logical col byte (XOR-swizzled)
    const unsigned short* aS[2][2];
    const unsigned short* bS[2][2];
#pragma unroll
    for (int H = 0; H < 2; ++H)
#pragma unroll
        for (int c = 0; c < 2; ++c) {
            int rA = (c << 7) | (H << 6) | t5;                               // swap67 inverse
            int rB = (((c << 1) | (t5 >> 5)) << 6) | (H << 5) | (t5 & 31);   // B inverse remap
            aS[H][c] = A + (size_t)(m0 + rA) * lda + (colb >> 1);
            bS[H][c] = BT + (size_t)(n0 + rB) * ldb + (colb >> 1);
        }

    // ---- fragment read offsets (element units, swizzle folded per-lane) ----
    int xorp = (lkg * 8) ^ ((lrow & 4) << 2);
    int aoff = wm * 4096 + lrow * 64 + xorp;
    int boff = wn * 2048 + lrow * 64 + xorp;

    f32x4 acc[8][4];
#pragma unroll
    for (int i = 0; i < 8; ++i)
#pragma unroll
        for (int j = 0; j < 4; ++j) acc[i][j] = (f32x4){0.f, 0.f, 0.f, 0.f};
    bf16x8 af[4][2], bf0[2][2], bf1[2][2];

    const int nkt = K >> 6;

    // prologue: tile0 fully, tile1 {A0,B1,A1} (B0 comes at tile0's ph1)
    STAGE_A(0, 0, 0); STAGE_A(0, 1, 0); STAGE_B(0, 0, 0); STAGE_B(0, 1, 0);
    STAGE_A(1, 0, 1); STAGE_B(1, 1, 1); STAGE_A(1, 1, 1);
    VM6;
    BARRIER();

    int t = 0;
    for (; t + 2 < nkt; ++t) KTILE(t & 1, t, KEEP, KEEP, VM6);
    KTILE(t & 1, t, KEEP, DROP, VM0);   // t = nkt-2: stage only (t+1).B0, drain
    ++t;
    KTILE(t & 1, t, DROP, DROP, VMNONE);  // t = nkt-1: read-only

    // ---- epilogue ----
#pragma unroll
    for (int ni = 0; ni < 4; ++ni) {
        int col = n0 + wn * 64 + ni * 16 + lrow;
        float bval = (col < nsplit) ? bias0[col] : bias1[col - nsplit];
        float scl = (col < nsplit) ? s0 : s1;
#pragma unroll
        for (int mi = 0; mi < 8; ++mi) {
            int row = m0 + wm * 128 + mi * 16 + lkg * 4;
#pragma unroll
            for (int j = 0; j < 4; ++j)
                C[(size_t)(row + j) * ldc + col] = cvt_bf((acc[mi][ni][j] + bval) * scl);
        }
    }
}

// ---------------- flash attention (swapped QK^T, exp2, packed P) ----------------
__global__ __launch_bounds__(256) void attn(const unsigned short* __restrict__ q, int ldq,
                                            const unsigned short* __restrict__ k, int ldk,
                                            const unsigned short* __restrict__ v, int ldv,
                                            float* __restrict__ out) {
    const int S = 1024, D = 5120, Dh = 40;
    int b = blockIdx.z, h = blockIdx.y, qt = blockIdx.x;
    int t = threadIdx.x, lane = t & 63, wid = t >> 6;
    int lrow = lane & 15, lkg = lane >> 4;

    __shared__ __align__(16) unsigned short Ks[64 * 72];
    __shared__ __align__(16) unsigned short Vs[64 * 72];
    __shared__ __align__(16) unsigned short Ps[4][16 * 72];

    const size_t qbase = ((size_t)b * S) * ldq + (size_t)h * Dh;
    const size_t kbase = ((size_t)b * S) * ldk + (size_t)h * Dh;
    const size_t vbase = ((size_t)b * S) * ldv + (size_t)h * Dh;
    int q0 = qt * 64 + wid * 16;

    bf16x8 qf0, qf1;
    {
        const unsigned short* qp = q + qbase + (size_t)(q0 + lrow) * ldq;
        qf0 = *(const bf16x8*)(qp + lkg * 8);
        qf1 = (lkg == 0) ? *(const bf16x8*)(qp + 32) : bf8_zero();
    }

    f32x4 acc[3];
#pragma unroll
    for (int nb = 0; nb < 3; ++nb) acc[nb] = (f32x4){0.f, 0.f, 0.f, 0.f};
    float mrun = -INFINITY, lrun = 0.f;

    for (int kt = 0; kt < 16; ++kt) {
        __syncthreads();
#pragma unroll
        for (int it = 0; it < 2; ++it) {
            int idx = t + it * 256;
            int rr = idx >> 3, cc = idx & 7;
            uint4 val = make_uint4(0, 0, 0, 0);
            if (cc < 5) val = *(const uint4*)(k + kbase + (size_t)(kt * 64 + rr) * ldk + cc * 8);
            *(uint4*)&Ks[rr * 72 + cc * 8] = val;
        }
#pragma unroll
        for (int it = 0; it < 2; ++it) {
            int idx = t + it * 256;
            int rr = idx & 63, cc = idx >> 6;
            if (cc < 6) {
                uint4 val = make_uint4(0, 0, 0, 0);
                if (cc < 5) val = *(const uint4*)(v + vbase + (size_t)(kt * 64 + rr) * ldv + cc * 8);
                const unsigned short* pv = (const unsigned short*)&val;
#pragma unroll
                for (int j = 0; j < 8; ++j) Vs[(cc * 8 + j) * 72 + rr] = pv[j];
            }
        }
        __syncthreads();

        f32x4 sf[4];
#pragma unroll
        for (int nb = 0; nb < 4; ++nb) {
            sf[nb] = (f32x4){0.f, 0.f, 0.f, 0.f};
            bf16x8 kf0 = *(const bf16x8*)&Ks[(nb * 16 + lrow) * 72 + lkg * 8];
            bf16x8 kf1 = *(const bf16x8*)&Ks[(nb * 16 + lrow) * 72 + 32 + lkg * 8];
            sf[nb] = MFMA16(kf0, qf0, sf[nb]);
            sf[nb] = MFMA16(kf1, qf1, sf[nb]);
        }

        float tm = sf[0][0];
#pragma unroll
        for (int nb = 0; nb < 4; ++nb)
#pragma unroll
            for (int i = 0; i < 4; ++i) tm = fmaxf(tm, sf[nb][i]);
        tm = fmaxf(tm, __shfl_xor(tm, 16));
        tm = fmaxf(tm, __shfl_xor(tm, 32));
        float mn = fmaxf(mrun, tm);
        float al = EXP2F(mrun - mn);
        mrun = mn;
        float rs = 0.f;
#pragma unroll
        for (int nb = 0; nb < 4; ++nb) {
            bf16x4 pk;
#pragma unroll
            for (int i = 0; i < 4; ++i) {
                float p = EXP2F(sf[nb][i] - mn);
                rs += p;
                pk[i] = (__bf16)p;
            }
            *(bf16x4*)&Ps[wid][lrow * 72 + nb * 16 + lkg * 4] = pk;
        }
        rs += __shfl_xor(rs, 16);
        rs += __shfl_xor(rs, 32);
        lrun = lrun * al + rs;

        float alr[4];
#pragma unroll
        for (int i = 0; i < 4; ++i) alr[i] = __shfl(al, lkg * 4 + i);
#pragma unroll
        for (int nb = 0; nb < 3; ++nb)
#pragma unroll
            for (int i = 0; i < 4; ++i) acc[nb][i] *= alr[i];

#pragma unroll
        for (int kk = 0; kk < 2; ++kk) {
            bf16x8 pf = *(const bf16x8*)&Ps[wid][lrow * 72 + kk * 32 + lkg * 8];
#pragma unroll
            for (int nb = 0; nb < 3; ++nb) {
                bf16x8 vf = *(const bf16x8*)&Vs[(nb * 16 + lrow) * 72 + kk * 32 + lkg * 8];
                acc[nb] = MFMA16(pf, vf, acc[nb]);
            }
        }
    }

    float lr[4];
#pragma unroll
    for (int i = 0; i < 4; ++i) lr[i] = __shfl(lrun, lkg * 4 + i);
#pragma unroll
    for (int i = 0; i < 4; ++i) {
        float inv = 1.0f / lr[i];
        int s = q0 + lkg * 4 + i;
#pragma unroll
        for (int nb = 0; nb < 3; ++nb) {
            int d = nb * 16 + lrow;
            if (d < Dh) out[((size_t)(b * S + s)) * D + h * Dh + d] = acc[nb][i] * inv;
        }
    }
}

extern "C" void kernel_launch(void* const* d_in, const int* in_sizes, int n_in,
                              void* d_out, int out_size, void* d_ws, size_t ws_size,
                              hipStream_t stream) {
    const int M = 2048, D = 5120, L = 1536, NQ = D + L /*6656*/, NKV = 2 * D /*10240*/;
    const float* x  = (const float*)d_in[0];
    const float* Wq = (const float*)d_in[1];
    const float* bq = (const float*)d_in[2];
    const float* Wc = (const float*)d_in[3];
    const float* bc = (const float*)d_in[4];
    const float* Wk = (const float*)d_in[5];
    const float* bk = (const float*)d_in[6];
    const float* Wv = (const float*)d_in[7];
    const float* bv = (const float*)d_in[8];
    float* out = (float*)d_out;

    unsigned short* ws = (unsigned short*)d_ws;
    size_t off = 0;
    unsigned short* xb    = ws + off; off += (size_t)M * D;
    unsigned short* WqcT  = ws + off; off += (size_t)NQ * D;   // [Wq|Wc]^T : [6656][5120]
    unsigned short* WkvT  = ws + off; off += (size_t)NKV * L;  // [Wk|Wv]^T : [10240][1536]
    unsigned short* qkvb  = ws + off; off += (size_t)M * NQ;   // [q | kv_latent]
    unsigned short* kvout = ws + off; off += (size_t)M * NKV;  // [k | v]

    xconv<<<(M * D) / 1024, 256, 0, stream>>>(x, xb, M * D);
    wconv<<<dim3(D / 32, D / 32), 256, 0, stream>>>(Wq, WqcT, D, D);
    wconv<<<dim3(L / 32, D / 32), 256, 0, stream>>>(Wc, WqcT + (size_t)D * D, D, L);
    wconv<<<dim3(D / 32, L / 32), 256, 0, stream>>>(Wk, WkvT, L, D);
    wconv<<<dim3(D / 32, L / 32), 256, 0, stream>>>(Wv, WkvT + (size_t)D * L, L, D);

    const float qscale = 1.4426950408889634f / 6.324555320336759f;  // log2(e)/sqrt(40)

    // GEMM1: [q | kv_latent] = x @ [Wq | Wc]   grid 8x26 = 208 (208%8==0)
    gemm256<<<dim3((NQ / 256) * (M / 256)), 512, 0, stream>>>(xb, D, WqcT, D, bq, bc, D,
                                                              qkvb, NQ, D, qscale, 1.0f,
                                                              NQ / 256);
    // GEMM2: [k | v] = kv_latent @ [Wk | Wv]   grid 8x40 = 320 (320%8==0)
    gemm256<<<dim3((NKV / 256) * (M / 256)), 512, 0, stream>>>(qkvb + D, NQ, WkvT, L, bk, bv, D,
                                                               kvout, NKV, L, 1.0f, 1.0f,
                                                               NKV / 256);

    attn<<<dim3(1024 / 64, 128, 2), 256, 0, stream>>>(qkvb, NQ, kvout, NKV, kvout + D, NKV, out);
}

// Round 4
// 538.011 us; speedup vs baseline: 1.3209x; 1.0295x over previous
//
#include <hip/hip_runtime.h>
#include <hip/hip_bf16.h>

typedef __attribute__((ext_vector_type(8))) __bf16 bf16x8;
typedef __attribute__((ext_vector_type(4))) __bf16 bf16x4;
typedef __attribute__((ext_vector_type(4))) float f32x4;

#define MFMA16(a, b, c) __builtin_amdgcn_mfma_f32_16x16x32_bf16((a), (b), (c), 0, 0, 0)

#if __has_builtin(__builtin_amdgcn_exp2f)
#define EXP2F(x) __builtin_amdgcn_exp2f(x)
#else
#define EXP2F(x) exp2f(x)
#endif

#define GLDS16(g, l)                                                             \
    __builtin_amdgcn_global_load_lds((const __attribute__((address_space(1))) void*)(g), \
                                     (__attribute__((address_space(3))) void*)(l), 16, 0, 0)

#define BARRIER()                          \
    do {                                   \
        asm volatile("" ::: "memory");     \
        __builtin_amdgcn_s_barrier();      \
        asm volatile("" ::: "memory");     \
    } while (0)

#define WAIT_LGKM0() asm volatile("s_waitcnt lgkmcnt(0)" ::: "memory")
#define VM6 asm volatile("s_waitcnt vmcnt(6)" ::: "memory")
#define VM0 asm volatile("s_waitcnt vmcnt(0)" ::: "memory")
#define VMNONE ((void)0)
#define KEEP(x) x
#define DROP(x)

static __device__ __forceinline__ unsigned short cvt_bf(float f) {
    return __builtin_bit_cast(unsigned short, (__bf16)f);
}

static __device__ __forceinline__ bf16x8 bf8_zero() {
    uint4 z = make_uint4(0, 0, 0, 0);
    return __builtin_bit_cast(bf16x8, z);
}

// ---------------- fp32 -> bf16 elementwise (x) ----------------
__global__ __launch_bounds__(256) void xconv(const float* __restrict__ X,
                                             unsigned short* __restrict__ Xb, int n) {
    int i = (blockIdx.x * 256 + threadIdx.x) * 4;
    if (i < n) {
        float4 f = *(const float4*)(X + i);
        ushort4 o;
        o.x = cvt_bf(f.x); o.y = cvt_bf(f.y); o.z = cvt_bf(f.z); o.w = cvt_bf(f.w);
        *(ushort4*)(Xb + i) = o;
    }
}

// ---------------- fp32 W[K][N] -> bf16 WT[N][K] ----------------
__global__ __launch_bounds__(256) void wconv(const float* __restrict__ W,
                                             unsigned short* __restrict__ WT, int K, int N) {
    __shared__ unsigned short tile[32][33];  // [k][n]
    int n0 = blockIdx.x * 32, k0 = blockIdx.y * 32;
    int c = threadIdx.x & 31, r8 = threadIdx.x >> 5;
#pragma unroll
    for (int it = 0; it < 4; ++it) {
        int r = r8 + it * 8;
        tile[r][c] = cvt_bf(W[(size_t)(k0 + r) * N + n0 + c]);
    }
    __syncthreads();
    int k2 = (threadIdx.x & 15) * 2, n8 = threadIdx.x >> 4;
#pragma unroll
    for (int it = 0; it < 2; ++it) {
        int n = n8 + it * 16;
        ushort2 o;
        o.x = tile[k2][n];
        o.y = tile[k2 + 1][n];
        *(ushort2*)&WT[(size_t)(n0 + n) * K + k0 + k2] = o;
    }
}

// ================= 256x256 8-phase bf16 GEMM (T1+T2+T3+T4+T5) =================
// C[M][N] = A[M][K] @ BT[N][K]^T + bias, *scale.  BM=BN=256, BK=64, 512 thr (2Mx4N waves).
// LDS: A/B double-buffered 2x32KB each = 128KB. Row = full BK (128B, 8 x 16B slots).
// Quadrant row remap (A: swap bits6/7; B: (r>>6)<<5 | r&31 within region H=(r>>5)&1)
// so staging can overwrite regions already consumed mid-tile.
// Bank swizzle: phys_slot = logical_slot ^ (row & 7)  (3-bit spread -> 16 lanes of a
// read phase cover all 8 slots of a 128B row, 2 lanes/slot = conflict-free).
// Applied on the pre-swizzled GLOBAL source at staging (LDS dest linear, rule #21)
// and on the ds_read addresses.

#define STAGE_A(S, H, KT)                                                              \
    do {                                                                               \
        GLDS16(aS[H][0] + (size_t)(KT) * 64, &Abuf[S][(H) * 8192 + wid * 512]);        \
        GLDS16(aS[H][1] + (size_t)(KT) * 64, &Abuf[S][(H) * 8192 + 4096 + wid * 512]); \
    } while (0)
#define STAGE_B(S, H, KT)                                                              \
    do {                                                                               \
        GLDS16(bS[H][0] + (size_t)(KT) * 64, &Bbuf[S][(H) * 8192 + wid * 512]);        \
        GLDS16(bS[H][1] + (size_t)(KT) * 64, &Bbuf[S][(H) * 8192 + 4096 + wid * 512]); \
    } while (0)

#define LDA_HALF(S, QM)                                                                   \
    do {                                                                                  \
        _Pragma("unroll") for (int mi = 0; mi < 4; ++mi)                                  \
            _Pragma("unroll") for (int kh = 0; kh < 2; ++kh)                              \
                af[mi][kh] =                                                              \
                    *(const bf16x8*)&Abuf[S][((QM) * 8192 + aoff + mi * 1024) ^ (kh * 32)]; \
    } while (0)
#define LDB_HALF(S, QN, BF)                                                               \
    do {                                                                                  \
        _Pragma("unroll") for (int ni = 0; ni < 2; ++ni)                                  \
            _Pragma("unroll") for (int kh = 0; kh < 2; ++kh)                              \
                BF[ni][kh] =                                                              \
                    *(const bf16x8*)&Bbuf[S][((QN) * 8192 + boff + ni * 1024) ^ (kh * 32)]; \
    } while (0)

#define MMAQ(QM, QN, BF)                                                                \
    do {                                                                                \
        _Pragma("unroll") for (int mi = 0; mi < 4; ++mi)                                \
            _Pragma("unroll") for (int ni = 0; ni < 2; ++ni)                            \
                _Pragma("unroll") for (int kh = 0; kh < 2; ++kh)                        \
                    acc[(QM) * 4 + mi][(QN) * 2 + ni] =                                 \
                        MFMA16(af[mi][kh], BF[ni][kh], acc[(QM) * 4 + mi][(QN) * 2 + ni]); \
    } while (0)

// One K-tile = 4 phases, quadrant order (0,0)->(0,1)->(1,1)->(1,0); bf0 stays live
// in registers so ph4 needs no B re-read. Stage plan (steady state, tile T, slot S):
//  ph1: read A0,B0 | stage (T+1).B0 -> S^1 ; ph2: read B1 | stage (T+2).A0 -> S
//  ph3: read A1    | stage (T+2).B1 -> S   ; ph4: (regs)  | stage (T+2).A1 -> S, vmcnt(6)
#define KTILE(S, T, STG1, STG234, VMOP)             \
    {                                               \
        const int s_ = (S);                         \
        LDA_HALF(s_, 0);                            \
        LDB_HALF(s_, 0, bf0);                       \
        STG1(STAGE_B(s_ ^ 1, 0, (T) + 1);)          \
        asm volatile("s_waitcnt lgkmcnt(8)" ::: "memory"); \
        BARRIER();                                  \
        WAIT_LGKM0();                               \
        __builtin_amdgcn_s_setprio(1);              \
        MMAQ(0, 0, bf0);                            \
        __builtin_amdgcn_s_setprio(0);              \
        BARRIER();                                  \
        LDB_HALF(s_, 1, bf1);                       \
        STG234(STAGE_A(s_, 0, (T) + 2);)            \
        BARRIER();                                  \
        WAIT_LGKM0();                               \
        __builtin_amdgcn_s_setprio(1);              \
        MMAQ(0, 1, bf1);                            \
        __builtin_amdgcn_s_setprio(0);              \
        BARRIER();                                  \
        LDA_HALF(s_, 1);                            \
        STG234(STAGE_B(s_, 1, (T) + 2);)            \
        BARRIER();                                  \
        WAIT_LGKM0();                               \
        __builtin_amdgcn_s_setprio(1);              \
        MMAQ(1, 1, bf1);                            \
        __builtin_amdgcn_s_setprio(0);              \
        BARRIER();                                  \
        STG234(STAGE_A(s_, 1, (T) + 2);)            \
        VMOP;                                       \
        BARRIER();                                  \
        __builtin_amdgcn_s_setprio(1);              \
        MMAQ(1, 0, bf0);                            \
        __builtin_amdgcn_s_setprio(0);              \
        BARRIER();                                  \
    }

__global__ __launch_bounds__(512, 2) void gemm256(const unsigned short* __restrict__ A, int lda,
                                                  const unsigned short* __restrict__ BT, int ldb,
                                                  const float* __restrict__ bias0,
                                                  const float* __restrict__ bias1, int nsplit,
                                                  unsigned short* __restrict__ C, int ldc,
                                                  int K, float s0, float s1, int gx) {
    __shared__ __align__(16) unsigned short Abuf[2][16384];  // 2 x 32KB
    __shared__ __align__(16) unsigned short Bbuf[2][16384];

    // XCD-aware bijective swizzle (gridDim.x % 8 == 0 by construction)
    int nwg = gridDim.x, orig = blockIdx.x;
    int cpx = nwg >> 3;
    int wgid = (orig & 7) * cpx + (orig >> 3);
    int tm = wgid / gx, tn = wgid % gx;
    int m0 = tm * 256, n0 = tn * 256;

    int tid = threadIdx.x, lane = tid & 63, wid = tid >> 6;
    int wm = wid >> 2, wn = wid & 3;
    int lrow = lane & 15, lkg = lane >> 4;

    // ---- staging source addresses (pre-swizzled global, linear LDS dest) ----
    // line (H,c): phys row R = c*64 + wid*8 + (l>>3), phys slot = l&7;
    // source logical slot = (l&7) ^ (R&7) = (l&7) ^ ((l>>3)&7).
    int t5 = tid >> 3;  // = wid*8 + (l>>3), 6 bits
    int cole = ((tid & 7) ^ ((tid >> 3) & 7)) << 3;  // logical col (elements)
    const unsigned short* aS[2][2];
    const unsigned short* bS[2][2];
#pragma unroll
    for (int H = 0; H < 2; ++H)
#pragma unroll
        for (int c = 0; c < 2; ++c) {
            int rA = (c << 7) | (H << 6) | t5;                               // swap67 inverse
            int rB = (((c << 1) | (t5 >> 5)) << 6) | (H << 5) | (t5 & 31);   // B inverse remap
            aS[H][c] = A + (size_t)(m0 + rA) * lda + cole;
            bS[H][c] = BT + (size_t)(n0 + rB) * ldb + cole;
        }

    // ---- fragment read offsets (elements); kh handled by XOR 32 (bit 5) ----
    int xorc = (lkg * 8) ^ ((lrow & 7) << 3);
    int aoff = wm * 4096 + lrow * 64 + xorc;
    int boff = wn * 2048 + lrow * 64 + xorc;

    f32x4 acc[8][4];
#pragma unroll
    for (int i = 0; i < 8; ++i)
#pragma unroll
        for (int j = 0; j < 4; ++j) acc[i][j] = (f32x4){0.f, 0.f, 0.f, 0.f};
    bf16x8 af[4][2], bf0[2][2], bf1[2][2];

    const int nkt = K >> 6;

    // prologue: tile0 fully, tile1 {A0,B1,A1} (B0 comes at tile0's ph1)
    STAGE_A(0, 0, 0); STAGE_A(0, 1, 0); STAGE_B(0, 0, 0); STAGE_B(0, 1, 0);
    STAGE_A(1, 0, 1); STAGE_B(1, 1, 1); STAGE_A(1, 1, 1);
    VM6;
    BARRIER();

    int t = 0;
    for (; t + 2 < nkt; ++t) KTILE(t & 1, t, KEEP, KEEP, VM6);
    KTILE(t & 1, t, KEEP, DROP, VM0);   // t = nkt-2: stage only (t+1).B0, drain
    ++t;
    KTILE(t & 1, t, DROP, DROP, VMNONE);  // t = nkt-1: read-only

    // ---- epilogue ----
#pragma unroll
    for (int ni = 0; ni < 4; ++ni) {
        int col = n0 + wn * 64 + ni * 16 + lrow;
        float bval = (col < nsplit) ? bias0[col] : bias1[col - nsplit];
        float scl = (col < nsplit) ? s0 : s1;
#pragma unroll
        for (int mi = 0; mi < 8; ++mi) {
            int row = m0 + wm * 128 + mi * 16 + lkg * 4;
#pragma unroll
            for (int j = 0; j < 4; ++j)
                C[(size_t)(row + j) * ldc + col] = cvt_bf((acc[mi][ni][j] + bval) * scl);
        }
    }
}

// ---------------- flash attention (swapped QK^T, exp2, packed P) ----------------
__global__ __launch_bounds__(256) void attn(const unsigned short* __restrict__ q, int ldq,
                                            const unsigned short* __restrict__ k, int ldk,
                                            const unsigned short* __restrict__ v, int ldv,
                                            float* __restrict__ out) {
    const int S = 1024, D = 5120, Dh = 40;
    int b = blockIdx.z, h = blockIdx.y, qt = blockIdx.x;
    int t = threadIdx.x, lane = t & 63, wid = t >> 6;
    int lrow = lane & 15, lkg = lane >> 4;

    __shared__ __align__(16) unsigned short Ks[64 * 72];
    __shared__ __align__(16) unsigned short Vs[64 * 72];
    __shared__ __align__(16) unsigned short Ps[4][16 * 72];

    const size_t qbase = ((size_t)b * S) * ldq + (size_t)h * Dh;
    const size_t kbase = ((size_t)b * S) * ldk + (size_t)h * Dh;
    const size_t vbase = ((size_t)b * S) * ldv + (size_t)h * Dh;
    int q0 = qt * 64 + wid * 16;

    bf16x8 qf0, qf1;
    {
        const unsigned short* qp = q + qbase + (size_t)(q0 + lrow) * ldq;
        qf0 = *(const bf16x8*)(qp + lkg * 8);
        qf1 = (lkg == 0) ? *(const bf16x8*)(qp + 32) : bf8_zero();
    }

    f32x4 acc[3];
#pragma unroll
    for (int nb = 0; nb < 3; ++nb) acc[nb] = (f32x4){0.f, 0.f, 0.f, 0.f};
    float mrun = -INFINITY, lrun = 0.f;

    for (int kt = 0; kt < 16; ++kt) {
        __syncthreads();
#pragma unroll
        for (int it = 0; it < 2; ++it) {
            int idx = t + it * 256;
            int rr = idx >> 3, cc = idx & 7;
            uint4 val = make_uint4(0, 0, 0, 0);
            if (cc < 5) val = *(const uint4*)(k + kbase + (size_t)(kt * 64 + rr) * ldk + cc * 8);
            *(uint4*)&Ks[rr * 72 + cc * 8] = val;
        }
#pragma unroll
        for (int it = 0; it < 2; ++it) {
            int idx = t + it * 256;
            int rr = idx & 63, cc = idx >> 6;
            if (cc < 6) {
                uint4 val = make_uint4(0, 0, 0, 0);
                if (cc < 5) val = *(const uint4*)(v + vbase + (size_t)(kt * 64 + rr) * ldv + cc * 8);
                const unsigned short* pv = (const unsigned short*)&val;
#pragma unroll
                for (int j = 0; j < 8; ++j) Vs[(cc * 8 + j) * 72 + rr] = pv[j];
            }
        }
        __syncthreads();

        f32x4 sf[4];
#pragma unroll
        for (int nb = 0; nb < 4; ++nb) {
            sf[nb] = (f32x4){0.f, 0.f, 0.f, 0.f};
            bf16x8 kf0 = *(const bf16x8*)&Ks[(nb * 16 + lrow) * 72 + lkg * 8];
            bf16x8 kf1 = *(const bf16x8*)&Ks[(nb * 16 + lrow) * 72 + 32 + lkg * 8];
            sf[nb] = MFMA16(kf0, qf0, sf[nb]);
            sf[nb] = MFMA16(kf1, qf1, sf[nb]);
        }

        float tm = sf[0][0];
#pragma unroll
        for (int nb = 0; nb < 4; ++nb)
#pragma unroll
            for (int i = 0; i < 4; ++i) tm = fmaxf(tm, sf[nb][i]);
        tm = fmaxf(tm, __shfl_xor(tm, 16));
        tm = fmaxf(tm, __shfl_xor(tm, 32));
        float mn = fmaxf(mrun, tm);
        float al = EXP2F(mrun - mn);
        mrun = mn;
        float rs = 0.f;
#pragma unroll
        for (int nb = 0; nb < 4; ++nb) {
            bf16x4 pk;
#pragma unroll
            for (int i = 0; i < 4; ++i) {
                float p = EXP2F(sf[nb][i] - mn);
                rs += p;
                pk[i] = (__bf16)p;
            }
            *(bf16x4*)&Ps[wid][lrow * 72 + nb * 16 + lkg * 4] = pk;
        }
        rs += __shfl_xor(rs, 16);
        rs += __shfl_xor(rs, 32);
        lrun = lrun * al + rs;

        float alr[4];
#pragma unroll
        for (int i = 0; i < 4; ++i) alr[i] = __shfl(al, lkg * 4 + i);
#pragma unroll
        for (int nb = 0; nb < 3; ++nb)
#pragma unroll
            for (int i = 0; i < 4; ++i) acc[nb][i] *= alr[i];

#pragma unroll
        for (int kk = 0; kk < 2; ++kk) {
            bf16x8 pf = *(const bf16x8*)&Ps[wid][lrow * 72 + kk * 32 + lkg * 8];
#pragma unroll
            for (int nb = 0; nb < 3; ++nb) {
                bf16x8 vf = *(const bf16x8*)&Vs[(nb * 16 + lrow) * 72 + kk * 32 + lkg * 8];
                acc[nb] = MFMA16(pf, vf, acc[nb]);
            }
        }
    }

    float lr[4];
#pragma unroll
    for (int i = 0; i < 4; ++i) lr[i] = __shfl(lrun, lkg * 4 + i);
#pragma unroll
    for (int i = 0; i < 4; ++i) {
        float inv = 1.0f / lr[i];
        int s = q0 + lkg * 4 + i;
#pragma unroll
        for (int nb = 0; nb < 3; ++nb) {
            int d = nb * 16 + lrow;
            if (d < Dh) out[((size_t)(b * S + s)) * D + h * Dh + d] = acc[nb][i] * inv;
        }
    }
}

extern "C" void kernel_launch(void* const* d_in, const int* in_sizes, int n_in,
                              void* d_out, int out_size, void* d_ws, size_t ws_size,
                              hipStream_t stream) {
    const int M = 2048, D = 5120, L = 1536, NQ = D + L /*6656*/, NKV = 2 * D /*10240*/;
    const float* x  = (const float*)d_in[0];
    const float* Wq = (const float*)d_in[1];
    const float* bq = (const float*)d_in[2];
    const float* Wc = (const float*)d_in[3];
    const float* bc = (const float*)d_in[4];
    const float* Wk = (const float*)d_in[5];
    const float* bk = (const float*)d_in[6];
    const float* Wv = (const float*)d_in[7];
    const float* bv = (const float*)d_in[8];
    float* out = (float*)d_out;

    unsigned short* ws = (unsigned short*)d_ws;
    size_t off = 0;
    unsigned short* xb    = ws + off; off += (size_t)M * D;
    unsigned short* WqcT  = ws + off; off += (size_t)NQ * D;   // [Wq|Wc]^T : [6656][5120]
    unsigned short* WkvT  = ws + off; off += (size_t)NKV * L;  // [Wk|Wv]^T : [10240][1536]
    unsigned short* qkvb  = ws + off; off += (size_t)M * NQ;   // [q | kv_latent]
    unsigned short* kvout = ws + off; off += (size_t)M * NKV;  // [k | v]

    xconv<<<(M * D) / 1024, 256, 0, stream>>>(x, xb, M * D);
    wconv<<<dim3(D / 32, D / 32), 256, 0, stream>>>(Wq, WqcT, D, D);
    wconv<<<dim3(L / 32, D / 32), 256, 0, stream>>>(Wc, WqcT + (size_t)D * D, D, L);
    wconv<<<dim3(D / 32, L / 32), 256, 0, stream>>>(Wk, WkvT, L, D);
    wconv<<<dim3(D / 32, L / 32), 256, 0, stream>>>(Wv, WkvT + (size_t)D * L, L, D);

    const float qscale = 1.4426950408889634f / 6.324555320336759f;  // log2(e)/sqrt(40)

    // GEMM1: [q | kv_latent] = x @ [Wq | Wc]   grid 8x26 = 208 (208%8==0)
    gemm256<<<dim3((NQ / 256) * (M / 256)), 512, 0, stream>>>(xb, D, WqcT, D, bq, bc, D,
                                                              qkvb, NQ, D, qscale, 1.0f,
                                                              NQ / 256);
    // GEMM2: [k | v] = kv_latent @ [Wk | Wv]   grid 8x40 = 320 (320%8==0)
    gemm256<<<dim3((NKV / 256) * (M / 256)), 512, 0, stream>>>(qkvb + D, NQ, WkvT, L, bk, bv, D,
                                                               kvout, NKV, L, 1.0f, 1.0f,
                                                               NKV / 256);

    attn<<<dim3(1024 / 64, 128, 2), 256, 0, stream>>>(qkvb, NQ, kvout, NKV, kvout + D, NKV, out);
}

// Round 5
// 511.358 us; speedup vs baseline: 1.3898x; 1.0521x over previous
//
#include <hip/hip_runtime.h>
#include <hip/hip_bf16.h>

typedef __attribute__((ext_vector_type(8))) __bf16 bf16x8;
typedef __attribute__((ext_vector_type(4))) __bf16 bf16x4;
typedef __attribute__((ext_vector_type(4))) float f32x4;

#define MFMA16(a, b, c) __builtin_amdgcn_mfma_f32_16x16x32_bf16((a), (b), (c), 0, 0, 0)

#if __has_builtin(__builtin_amdgcn_exp2f)
#define EXP2F(x) __builtin_amdgcn_exp2f(x)
#else
#define EXP2F(x) exp2f(x)
#endif

#define GLDS16(g, l)                                                             \
    __builtin_amdgcn_global_load_lds((const __attribute__((address_space(1))) void*)(g), \
                                     (__attribute__((address_space(3))) void*)(l), 16, 0, 0)

#define BARRIER()                          \
    do {                                   \
        asm volatile("" ::: "memory");     \
        __builtin_amdgcn_s_barrier();      \
        asm volatile("" ::: "memory");     \
    } while (0)

#define WAIT_LGKM0() asm volatile("s_waitcnt lgkmcnt(0)" ::: "memory")
#define VM6 asm volatile("s_waitcnt vmcnt(6)" ::: "memory")
#define VM8 asm volatile("s_waitcnt vmcnt(8)" ::: "memory")
#define VM0 asm volatile("s_waitcnt vmcnt(0)" ::: "memory")
#define VMNONE ((void)0)
#define KEEP(x) x
#define DROP(x)

static __device__ __forceinline__ unsigned short cvt_bf(float f) {
    return __builtin_bit_cast(unsigned short, (__bf16)f);
}

static __device__ __forceinline__ bf16x8 bf8_zero() {
    uint4 z = make_uint4(0, 0, 0, 0);
    return __builtin_bit_cast(bf16x8, z);
}

// ---------------- fp32 -> bf16 elementwise (x) ----------------
__global__ __launch_bounds__(256) void xconv(const float* __restrict__ X,
                                             unsigned short* __restrict__ Xb, int n) {
    int i = (blockIdx.x * 256 + threadIdx.x) * 4;
    if (i < n) {
        float4 f = *(const float4*)(X + i);
        ushort4 o;
        o.x = cvt_bf(f.x); o.y = cvt_bf(f.y); o.z = cvt_bf(f.z); o.w = cvt_bf(f.w);
        *(ushort4*)(Xb + i) = o;
    }
}

// ---------------- fp32 W[K][N] -> bf16 WT[N][K] ----------------
__global__ __launch_bounds__(256) void wconv(const float* __restrict__ W,
                                             unsigned short* __restrict__ WT, int K, int N) {
    __shared__ unsigned short tile[32][33];  // [k][n]
    int n0 = blockIdx.x * 32, k0 = blockIdx.y * 32;
    int c = threadIdx.x & 31, r8 = threadIdx.x >> 5;
#pragma unroll
    for (int it = 0; it < 4; ++it) {
        int r = r8 + it * 8;
        tile[r][c] = cvt_bf(W[(size_t)(k0 + r) * N + n0 + c]);
    }
    __syncthreads();
    int k2 = (threadIdx.x & 15) * 2, n8 = threadIdx.x >> 4;
#pragma unroll
    for (int it = 0; it < 2; ++it) {
        int n = n8 + it * 16;
        ushort2 o;
        o.x = tile[k2][n];
        o.y = tile[k2 + 1][n];
        *(ushort2*)&WT[(size_t)(n0 + n) * K + k0 + k2] = o;
    }
}

// ================= 256x256 8-phase bf16 GEMM (unchanged control) =================
#define STAGE_A(S, H, KT)                                                              \
    do {                                                                               \
        GLDS16(aS[H][0] + (size_t)(KT) * 64, &Abuf[S][(H) * 8192 + wid * 512]);        \
        GLDS16(aS[H][1] + (size_t)(KT) * 64, &Abuf[S][(H) * 8192 + 4096 + wid * 512]); \
    } while (0)
#define STAGE_B(S, H, KT)                                                              \
    do {                                                                               \
        GLDS16(bS[H][0] + (size_t)(KT) * 64, &Bbuf[S][(H) * 8192 + wid * 512]);        \
        GLDS16(bS[H][1] + (size_t)(KT) * 64, &Bbuf[S][(H) * 8192 + 4096 + wid * 512]); \
    } while (0)

#define LDA_HALF(S, QM)                                                                   \
    do {                                                                                  \
        _Pragma("unroll") for (int mi = 0; mi < 4; ++mi)                                  \
            _Pragma("unroll") for (int kh = 0; kh < 2; ++kh)                              \
                af[mi][kh] =                                                              \
                    *(const bf16x8*)&Abuf[S][((QM) * 8192 + aoff + mi * 1024) ^ (kh * 32)]; \
    } while (0)
#define LDB_HALF(S, QN, BF)                                                               \
    do {                                                                                  \
        _Pragma("unroll") for (int ni = 0; ni < 2; ++ni)                                  \
            _Pragma("unroll") for (int kh = 0; kh < 2; ++kh)                              \
                BF[ni][kh] =                                                              \
                    *(const bf16x8*)&Bbuf[S][((QN) * 8192 + boff + ni * 1024) ^ (kh * 32)]; \
    } while (0)

#define MMAQ(QM, QN, BF)                                                                \
    do {                                                                                \
        _Pragma("unroll") for (int mi = 0; mi < 4; ++mi)                                \
            _Pragma("unroll") for (int ni = 0; ni < 2; ++ni)                            \
                _Pragma("unroll") for (int kh = 0; kh < 2; ++kh)                        \
                    acc[(QM) * 4 + mi][(QN) * 2 + ni] =                                 \
                        MFMA16(af[mi][kh], BF[ni][kh], acc[(QM) * 4 + mi][(QN) * 2 + ni]); \
    } while (0)

#define KTILE(S, T, STG1, STG234, VMOP)             \
    {                                               \
        const int s_ = (S);                         \
        LDA_HALF(s_, 0);                            \
        LDB_HALF(s_, 0, bf0);                       \
        STG1(STAGE_B(s_ ^ 1, 0, (T) + 1);)          \
        asm volatile("s_waitcnt lgkmcnt(8)" ::: "memory"); \
        BARRIER();                                  \
        WAIT_LGKM0();                               \
        __builtin_amdgcn_s_setprio(1);              \
        MMAQ(0, 0, bf0);                            \
        __builtin_amdgcn_s_setprio(0);              \
        BARRIER();                                  \
        LDB_HALF(s_, 1, bf1);                       \
        STG234(STAGE_A(s_, 0, (T) + 2);)            \
        BARRIER();                                  \
        WAIT_LGKM0();                               \
        __builtin_amdgcn_s_setprio(1);              \
        MMAQ(0, 1, bf1);                            \
        __builtin_amdgcn_s_setprio(0);              \
        BARRIER();                                  \
        LDA_HALF(s_, 1);                            \
        STG234(STAGE_B(s_, 1, (T) + 2);)            \
        BARRIER();                                  \
        WAIT_LGKM0();                               \
        __builtin_amdgcn_s_setprio(1);              \
        MMAQ(1, 1, bf1);                            \
        __builtin_amdgcn_s_setprio(0);              \
        BARRIER();                                  \
        STG234(STAGE_A(s_, 1, (T) + 2);)            \
        VMOP;                                       \
        BARRIER();                                  \
        __builtin_amdgcn_s_setprio(1);              \
        MMAQ(1, 0, bf0);                            \
        __builtin_amdgcn_s_setprio(0);              \
        BARRIER();                                  \
    }

__global__ __launch_bounds__(512, 2) void gemm256(const unsigned short* __restrict__ A, int lda,
                                                  const unsigned short* __restrict__ BT, int ldb,
                                                  const float* __restrict__ bias0,
                                                  const float* __restrict__ bias1, int nsplit,
                                                  unsigned short* __restrict__ C, int ldc,
                                                  int K, float s0, float s1, int gx) {
    __shared__ __align__(16) unsigned short Abuf[2][16384];  // 2 x 32KB
    __shared__ __align__(16) unsigned short Bbuf[2][16384];

    int nwg = gridDim.x, orig = blockIdx.x;
    int cpx = nwg >> 3;
    int wgid = (orig & 7) * cpx + (orig >> 3);
    int tm = wgid / gx, tn = wgid % gx;
    int m0 = tm * 256, n0 = tn * 256;

    int tid = threadIdx.x, lane = tid & 63, wid = tid >> 6;
    int wm = wid >> 2, wn = wid & 3;
    int lrow = lane & 15, lkg = lane >> 4;

    int t5 = tid >> 3;
    int cole = ((tid & 7) ^ ((tid >> 3) & 7)) << 3;
    const unsigned short* aS[2][2];
    const unsigned short* bS[2][2];
#pragma unroll
    for (int H = 0; H < 2; ++H)
#pragma unroll
        for (int c = 0; c < 2; ++c) {
            int rA = (c << 7) | (H << 6) | t5;
            int rB = (((c << 1) | (t5 >> 5)) << 6) | (H << 5) | (t5 & 31);
            aS[H][c] = A + (size_t)(m0 + rA) * lda + cole;
            bS[H][c] = BT + (size_t)(n0 + rB) * ldb + cole;
        }

    int xorc = (lkg * 8) ^ ((lrow & 7) << 3);
    int aoff = wm * 4096 + lrow * 64 + xorc;
    int boff = wn * 2048 + lrow * 64 + xorc;

    f32x4 acc[8][4];
#pragma unroll
    for (int i = 0; i < 8; ++i)
#pragma unroll
        for (int j = 0; j < 4; ++j) acc[i][j] = (f32x4){0.f, 0.f, 0.f, 0.f};
    bf16x8 af[4][2], bf0[2][2], bf1[2][2];

    const int nkt = K >> 6;

    STAGE_A(0, 0, 0); STAGE_A(0, 1, 0); STAGE_B(0, 0, 0); STAGE_B(0, 1, 0);
    STAGE_A(1, 0, 1); STAGE_B(1, 1, 1); STAGE_A(1, 1, 1);
    VM6;
    BARRIER();

    int t = 0;
    for (; t + 2 < nkt; ++t) KTILE(t & 1, t, KEEP, KEEP, VM6);
    KTILE(t & 1, t, KEEP, DROP, VM0);
    ++t;
    KTILE(t & 1, t, DROP, DROP, VMNONE);

#pragma unroll
    for (int ni = 0; ni < 4; ++ni) {
        int col = n0 + wn * 64 + ni * 16 + lrow;
        float bval = (col < nsplit) ? bias0[col] : bias1[col - nsplit];
        float scl = (col < nsplit) ? s0 : s1;
#pragma unroll
        for (int mi = 0; mi < 8; ++mi) {
            int row = m0 + wm * 128 + mi * 16 + lkg * 4;
#pragma unroll
            for (int j = 0; j < 4; ++j)
                C[(size_t)(row + j) * ldc + col] = cvt_bf((acc[mi][ni][j] + bval) * scl);
        }
    }
}

// ================= 128x128 2-blocks/CU bf16 GEMM (new, for GEMM2) =================
// BM=BN=128, BK=64, 256 thr (4 waves, 2Mx2N, wave tile 64x64). LDS 64KB (2 blocks/CU).
// Double-buffered; counted vmcnt(8) keeps next tile's 8 staging loads in flight
// across the barrier (drains to 0 only at the last tile). Same slot^(row&7) XOR
// swizzle (pre-swizzled global source, linear gload_lds dest, swizzled ds_read).
#define STG128(S, KT)                                                                  \
    do {                                                                               \
        _Pragma("unroll") for (int i_ = 0; i_ < 4; ++i_)                               \
            GLDS16(Ag + (size_t)(i_ * 32) * lda + (size_t)(KT) * 64,                   \
                   &Abuf[S][i_ * 2048 + wid * 512]);                                   \
        _Pragma("unroll") for (int i_ = 0; i_ < 4; ++i_)                               \
            GLDS16(Bg + (size_t)(i_ * 32) * ldb + (size_t)(KT) * 64,                   \
                   &Bbuf[S][i_ * 2048 + wid * 512]);                                   \
    } while (0)

__global__ __launch_bounds__(256, 2) void gemm128(const unsigned short* __restrict__ A, int lda,
                                                  const unsigned short* __restrict__ BT, int ldb,
                                                  const float* __restrict__ bias0,
                                                  const float* __restrict__ bias1, int nsplit,
                                                  unsigned short* __restrict__ C, int ldc,
                                                  int K, float s0, float s1, int gy) {
    __shared__ __align__(16) unsigned short Abuf[2][8192];  // 2 x 16KB
    __shared__ __align__(16) unsigned short Bbuf[2][8192];

    int b = blockIdx.x;
    int tm = b % gy, tn = b / gy;  // tm-inner: XCD=b%8 keeps A-panels L2-resident, tn synced
    int m0 = tm * 128, n0 = tn * 128;
    int tid = threadIdx.x, lane = tid & 63, wid = tid >> 6;
    int wm = wid >> 1, wn = wid & 1;
    int lrow = lane & 15, lkg = lane >> 4;

    // staging: thread t, instr i covers LDS bytes i*4096 + t*16
    //   -> row = i*32 + (t>>3), phys slot = t&7; source logical slot = (t&7)^((t>>3)&7)
    int srow = tid >> 3;
    int cole = ((tid & 7) ^ ((tid >> 3) & 7)) << 3;
    const unsigned short* Ag = A + (size_t)(m0 + srow) * lda + cole;
    const unsigned short* Bg = BT + (size_t)(n0 + srow) * ldb + cole;

    // fragment read: row r, k = kh*32 + lkg*8 -> slot (kh*4+lkg)^(lrow&7)
    int xorc8 = (lrow & 7) << 3;
    int aoff = (wm * 64 + lrow) * 64;
    int boff = (wn * 64 + lrow) * 64;

    f32x4 acc[4][4];
#pragma unroll
    for (int i = 0; i < 4; ++i)
#pragma unroll
        for (int j = 0; j < 4; ++j) acc[i][j] = (f32x4){0.f, 0.f, 0.f, 0.f};

    const int nkt = K >> 6;
    STG128(0, 0);
    for (int t = 0; t < nkt; ++t) {
        const int cur = t & 1;
        if (t + 1 < nkt) {
            STG128(cur ^ 1, t + 1);
            VM8;  // wait tile t landed; tile t+1's 8 loads stay in flight
        } else {
            VM0;
        }
        BARRIER();
        bf16x8 af[4][2], bv[4][2];
#pragma unroll
        for (int mi = 0; mi < 4; ++mi)
#pragma unroll
            for (int kh = 0; kh < 2; ++kh)
                af[mi][kh] = *(const bf16x8*)&Abuf[cur][aoff + mi * 1024 + (((kh * 4 + lkg) << 3) ^ xorc8)];
#pragma unroll
        for (int ni = 0; ni < 4; ++ni)
#pragma unroll
            for (int kh = 0; kh < 2; ++kh)
                bv[ni][kh] = *(const bf16x8*)&Bbuf[cur][boff + ni * 1024 + (((kh * 4 + lkg) << 3) ^ xorc8)];
        __builtin_amdgcn_s_setprio(1);
#pragma unroll
        for (int mi = 0; mi < 4; ++mi)
#pragma unroll
            for (int ni = 0; ni < 4; ++ni)
#pragma unroll
                for (int kh = 0; kh < 2; ++kh)
                    acc[mi][ni] = MFMA16(af[mi][kh], bv[ni][kh], acc[mi][ni]);
        __builtin_amdgcn_s_setprio(0);
        BARRIER();
    }

#pragma unroll
    for (int ni = 0; ni < 4; ++ni) {
        int col = n0 + wn * 64 + ni * 16 + lrow;
        float bval = (col < nsplit) ? bias0[col] : bias1[col - nsplit];
        float scl = (col < nsplit) ? s0 : s1;
#pragma unroll
        for (int mi = 0; mi < 4; ++mi) {
            int row = m0 + wm * 64 + mi * 16 + lkg * 4;
#pragma unroll
            for (int j = 0; j < 4; ++j)
                C[(size_t)(row + j) * ldc + col] = cvt_bf((acc[mi][ni][j] + bval) * scl);
        }
    }
}

// ---------------- flash attention (swapped QK^T, exp2, packed P) ----------------
__global__ __launch_bounds__(256) void attn(const unsigned short* __restrict__ q, int ldq,
                                            const unsigned short* __restrict__ k, int ldk,
                                            const unsigned short* __restrict__ v, int ldv,
                                            float* __restrict__ out) {
    const int S = 1024, D = 5120, Dh = 40;
    int b = blockIdx.z, h = blockIdx.y, qt = blockIdx.x;
    int t = threadIdx.x, lane = t & 63, wid = t >> 6;
    int lrow = lane & 15, lkg = lane >> 4;

    __shared__ __align__(16) unsigned short Ks[64 * 72];
    __shared__ __align__(16) unsigned short Vs[64 * 72];
    __shared__ __align__(16) unsigned short Ps[4][16 * 72];

    const size_t qbase = ((size_t)b * S) * ldq + (size_t)h * Dh;
    const size_t kbase = ((size_t)b * S) * ldk + (size_t)h * Dh;
    const size_t vbase = ((size_t)b * S) * ldv + (size_t)h * Dh;
    int q0 = qt * 64 + wid * 16;

    bf16x8 qf0, qf1;
    {
        const unsigned short* qp = q + qbase + (size_t)(q0 + lrow) * ldq;
        qf0 = *(const bf16x8*)(qp + lkg * 8);
        qf1 = (lkg == 0) ? *(const bf16x8*)(qp + 32) : bf8_zero();
    }

    f32x4 acc[3];
#pragma unroll
    for (int nb = 0; nb < 3; ++nb) acc[nb] = (f32x4){0.f, 0.f, 0.f, 0.f};
    float mrun = -INFINITY, lrun = 0.f;

    for (int kt = 0; kt < 16; ++kt) {
        __syncthreads();
#pragma unroll
        for (int it = 0; it < 2; ++it) {
            int idx = t + it * 256;
            int rr = idx >> 3, cc = idx & 7;
            uint4 val = make_uint4(0, 0, 0, 0);
            if (cc < 5) val = *(const uint4*)(k + kbase + (size_t)(kt * 64 + rr) * ldk + cc * 8);
            *(uint4*)&Ks[rr * 72 + cc * 8] = val;
        }
#pragma unroll
        for (int it = 0; it < 2; ++it) {
            int idx = t + it * 256;
            int rr = idx & 63, cc = idx >> 6;
            if (cc < 6) {
                uint4 val = make_uint4(0, 0, 0, 0);
                if (cc < 5) val = *(const uint4*)(v + vbase + (size_t)(kt * 64 + rr) * ldv + cc * 8);
                const unsigned short* pv = (const unsigned short*)&val;
#pragma unroll
                for (int j = 0; j < 8; ++j) Vs[(cc * 8 + j) * 72 + rr] = pv[j];
            }
        }
        __syncthreads();

        f32x4 sf[4];
#pragma unroll
        for (int nb = 0; nb < 4; ++nb) {
            sf[nb] = (f32x4){0.f, 0.f, 0.f, 0.f};
            bf16x8 kf0 = *(const bf16x8*)&Ks[(nb * 16 + lrow) * 72 + lkg * 8];
            bf16x8 kf1 = *(const bf16x8*)&Ks[(nb * 16 + lrow) * 72 + 32 + lkg * 8];
            sf[nb] = MFMA16(kf0, qf0, sf[nb]);
            sf[nb] = MFMA16(kf1, qf1, sf[nb]);
        }

        float tm = sf[0][0];
#pragma unroll
        for (int nb = 0; nb < 4; ++nb)
#pragma unroll
            for (int i = 0; i < 4; ++i) tm = fmaxf(tm, sf[nb][i]);
        tm = fmaxf(tm, __shfl_xor(tm, 16));
        tm = fmaxf(tm, __shfl_xor(tm, 32));
        float mn = fmaxf(mrun, tm);
        float al = EXP2F(mrun - mn);
        mrun = mn;
        float rs = 0.f;
#pragma unroll
        for (int nb = 0; nb < 4; ++nb) {
            bf16x4 pk;
#pragma unroll
            for (int i = 0; i < 4; ++i) {
                float p = EXP2F(sf[nb][i] - mn);
                rs += p;
                pk[i] = (__bf16)p;
            }
            *(bf16x4*)&Ps[wid][lrow * 72 + nb * 16 + lkg * 4] = pk;
        }
        rs += __shfl_xor(rs, 16);
        rs += __shfl_xor(rs, 32);
        lrun = lrun * al + rs;

        float alr[4];
#pragma unroll
        for (int i = 0; i < 4; ++i) alr[i] = __shfl(al, lkg * 4 + i);
#pragma unroll
        for (int nb = 0; nb < 3; ++nb)
#pragma unroll
            for (int i = 0; i < 4; ++i) acc[nb][i] *= alr[i];

#pragma unroll
        for (int kk = 0; kk < 2; ++kk) {
            bf16x8 pf = *(const bf16x8*)&Ps[wid][lrow * 72 + kk * 32 + lkg * 8];
#pragma unroll
            for (int nb = 0; nb < 3; ++nb) {
                bf16x8 vf = *(const bf16x8*)&Vs[(nb * 16 + lrow) * 72 + kk * 32 + lkg * 8];
                acc[nb] = MFMA16(pf, vf, acc[nb]);
            }
        }
    }

    float lr[4];
#pragma unroll
    for (int i = 0; i < 4; ++i) lr[i] = __shfl(lrun, lkg * 4 + i);
#pragma unroll
    for (int i = 0; i < 4; ++i) {
        float inv = 1.0f / lr[i];
        int s = q0 + lkg * 4 + i;
#pragma unroll
        for (int nb = 0; nb < 3; ++nb) {
            int d = nb * 16 + lrow;
            if (d < Dh) out[((size_t)(b * S + s)) * D + h * Dh + d] = acc[nb][i] * inv;
        }
    }
}

extern "C" void kernel_launch(void* const* d_in, const int* in_sizes, int n_in,
                              void* d_out, int out_size, void* d_ws, size_t ws_size,
                              hipStream_t stream) {
    const int M = 2048, D = 5120, L = 1536, NQ = D + L /*6656*/, NKV = 2 * D /*10240*/;
    const float* x  = (const float*)d_in[0];
    const float* Wq = (const float*)d_in[1];
    const float* bq = (const float*)d_in[2];
    const float* Wc = (const float*)d_in[3];
    const float* bc = (const float*)d_in[4];
    const float* Wk = (const float*)d_in[5];
    const float* bk = (const float*)d_in[6];
    const float* Wv = (const float*)d_in[7];
    const float* bv = (const float*)d_in[8];
    float* out = (float*)d_out;

    unsigned short* ws = (unsigned short*)d_ws;
    size_t off = 0;
    unsigned short* xb    = ws + off; off += (size_t)M * D;
    unsigned short* WqcT  = ws + off; off += (size_t)NQ * D;   // [Wq|Wc]^T : [6656][5120]
    unsigned short* WkvT  = ws + off; off += (size_t)NKV * L;  // [Wk|Wv]^T : [10240][1536]
    unsigned short* qkvb  = ws + off; off += (size_t)M * NQ;   // [q | kv_latent]
    unsigned short* kvout = ws + off; off += (size_t)M * NKV;  // [k | v]

    xconv<<<(M * D) / 1024, 256, 0, stream>>>(x, xb, M * D);
    wconv<<<dim3(D / 32, D / 32), 256, 0, stream>>>(Wq, WqcT, D, D);
    wconv<<<dim3(L / 32, D / 32), 256, 0, stream>>>(Wc, WqcT + (size_t)D * D, D, L);
    wconv<<<dim3(D / 32, L / 32), 256, 0, stream>>>(Wk, WkvT, L, D);
    wconv<<<dim3(D / 32, L / 32), 256, 0, stream>>>(Wv, WkvT + (size_t)D * L, L, D);

    const float qscale = 1.4426950408889634f / 6.324555320336759f;  // log2(e)/sqrt(40)

    // GEMM1: [q | kv_latent] = x @ [Wq | Wc]   grid 208 (8x26), 256^2 8-phase
    gemm256<<<dim3((NQ / 256) * (M / 256)), 512, 0, stream>>>(xb, D, WqcT, D, bq, bc, D,
                                                              qkvb, NQ, D, qscale, 1.0f,
                                                              NQ / 256);
    // GEMM2: [k | v] = kv_latent @ [Wk | Wv]   grid 1280 (80x16), 128^2 2-blocks/CU
    gemm128<<<dim3((NKV / 128) * (M / 128)), 256, 0, stream>>>(qkvb + D, NQ, WkvT, L, bk, bv, D,
                                                               kvout, NKV, L, 1.0f, 1.0f,
                                                               M / 128);

    attn<<<dim3(1024 / 64, 128, 2), 256, 0, stream>>>(qkvb, NQ, kvout, NKV, kvout + D, NKV, out);
}

// Round 6
// 490.242 us; speedup vs baseline: 1.4496x; 1.0431x over previous
//
#include <hip/hip_runtime.h>
#include <hip/hip_bf16.h>

typedef __attribute__((ext_vector_type(8))) __bf16 bf16x8;
typedef __attribute__((ext_vector_type(4))) __bf16 bf16x4;
typedef __attribute__((ext_vector_type(4))) float f32x4;

#define MFMA16(a, b, c) __builtin_amdgcn_mfma_f32_16x16x32_bf16((a), (b), (c), 0, 0, 0)

#if __has_builtin(__builtin_amdgcn_exp2f)
#define EXP2F(x) __builtin_amdgcn_exp2f(x)
#else
#define EXP2F(x) exp2f(x)
#endif

#define GLDS16(g, l)                                                             \
    __builtin_amdgcn_global_load_lds((const __attribute__((address_space(1))) void*)(g), \
                                     (__attribute__((address_space(3))) void*)(l), 16, 0, 0)

#define BARRIER()                          \
    do {                                   \
        asm volatile("" ::: "memory");     \
        __builtin_amdgcn_s_barrier();      \
        asm volatile("" ::: "memory");     \
    } while (0)

#define WAIT_LGKM0() asm volatile("s_waitcnt lgkmcnt(0)" ::: "memory")
#define VM6 asm volatile("s_waitcnt vmcnt(6)" ::: "memory")
#define VM8 asm volatile("s_waitcnt vmcnt(8)" ::: "memory")
#define VM0 asm volatile("s_waitcnt vmcnt(0)" ::: "memory")
#define VMNONE ((void)0)
#define KEEP(x) x
#define DROP(x)

static __device__ __forceinline__ unsigned short cvt_bf(float f) {
    return __builtin_bit_cast(unsigned short, (__bf16)f);
}

static __device__ __forceinline__ bf16x8 bf8_zero() {
    uint4 z = make_uint4(0, 0, 0, 0);
    return __builtin_bit_cast(bf16x8, z);
}

// ---------------- fp32 -> bf16 elementwise (x) ----------------
__global__ __launch_bounds__(256) void xconv(const float* __restrict__ X,
                                             unsigned short* __restrict__ Xb, int n) {
    int i = (blockIdx.x * 256 + threadIdx.x) * 4;
    if (i < n) {
        float4 f = *(const float4*)(X + i);
        ushort4 o;
        o.x = cvt_bf(f.x); o.y = cvt_bf(f.y); o.z = cvt_bf(f.z); o.w = cvt_bf(f.w);
        *(ushort4*)(Xb + i) = o;
    }
}

// ---------------- fp32 W[K][N] -> bf16 WT[N][K] ----------------
__global__ __launch_bounds__(256) void wconv(const float* __restrict__ W,
                                             unsigned short* __restrict__ WT, int K, int N) {
    __shared__ unsigned short tile[32][33];  // [k][n]
    int n0 = blockIdx.x * 32, k0 = blockIdx.y * 32;
    int c = threadIdx.x & 31, r8 = threadIdx.x >> 5;
#pragma unroll
    for (int it = 0; it < 4; ++it) {
        int r = r8 + it * 8;
        tile[r][c] = cvt_bf(W[(size_t)(k0 + r) * N + n0 + c]);
    }
    __syncthreads();
    int k2 = (threadIdx.x & 15) * 2, n8 = threadIdx.x >> 4;
#pragma unroll
    for (int it = 0; it < 2; ++it) {
        int n = n8 + it * 16;
        ushort2 o;
        o.x = tile[k2][n];
        o.y = tile[k2 + 1][n];
        *(ushort2*)&WT[(size_t)(n0 + n) * K + k0 + k2] = o;
    }
}

// ================= 256x256 pipelined bf16 GEMM (KTILE_V2: 3 barriers/K-tile) ======
// Same geometry/layout/swizzle as before; schedule reworked so ds_reads and
// stage-writes are issued UNDER the MFMA clusters (compiler's counted lgkmcnt
// handles per-wave data deps). Explicit lgkm0+barrier only where staging
// overwrites a region other waves may still be reading (3 points per K-tile).

#define STAGE_A(S, H, KT)                                                              \
    do {                                                                               \
        GLDS16(aS[H][0] + (size_t)(KT) * 64, &Abuf[S][(H) * 8192 + wid * 512]);        \
        GLDS16(aS[H][1] + (size_t)(KT) * 64, &Abuf[S][(H) * 8192 + 4096 + wid * 512]); \
    } while (0)
#define STAGE_B(S, H, KT)                                                              \
    do {                                                                               \
        GLDS16(bS[H][0] + (size_t)(KT) * 64, &Bbuf[S][(H) * 8192 + wid * 512]);        \
        GLDS16(bS[H][1] + (size_t)(KT) * 64, &Bbuf[S][(H) * 8192 + 4096 + wid * 512]); \
    } while (0)

#define LDA_HALF(S, QM)                                                                   \
    do {                                                                                  \
        _Pragma("unroll") for (int mi = 0; mi < 4; ++mi)                                  \
            _Pragma("unroll") for (int kh = 0; kh < 2; ++kh)                              \
                af[mi][kh] =                                                              \
                    *(const bf16x8*)&Abuf[S][((QM) * 8192 + aoff + mi * 1024) ^ (kh * 32)]; \
    } while (0)
#define LDB_HALF(S, QN, BF)                                                               \
    do {                                                                                  \
        _Pragma("unroll") for (int ni = 0; ni < 2; ++ni)                                  \
            _Pragma("unroll") for (int kh = 0; kh < 2; ++kh)                              \
                BF[ni][kh] =                                                              \
                    *(const bf16x8*)&Bbuf[S][((QN) * 8192 + boff + ni * 1024) ^ (kh * 32)]; \
    } while (0)

#define MMAQ(QM, QN, BF)                                                                \
    do {                                                                                \
        _Pragma("unroll") for (int mi = 0; mi < 4; ++mi)                                \
            _Pragma("unroll") for (int ni = 0; ni < 2; ++ni)                            \
                _Pragma("unroll") for (int kh = 0; kh < 2; ++kh)                        \
                    acc[(QM) * 4 + mi][(QN) * 2 + ni] =                                 \
                        MFMA16(af[mi][kh], BF[ni][kh], acc[(QM) * 4 + mi][(QN) * 2 + ni]); \
    } while (0)

// Pipelined K-tile. On entry: R1(T)={A0->af, B0->bf0} issued (prev tile's tail).
// MMAQ order (0,0)->(0,1)->(1,1)->(1,0); af reloaded mid-tile, bf0 persists.
// vmcnt(6) at tail = exactly the 8 oldest loads (= all stages targeting the
// S^1 regions the next R1 reads); verified incl. prologue and tail tiles.
#define KTILE_V2(S, T, STG1, STG2, VMOP, RDNEXT)       \
    {                                                  \
        const int s_ = (S);                            \
        LDB_HALF(s_, 1, bf1);                          \
        STG1(STAGE_B(s_ ^ 1, 0, (T) + 1);)             \
        __builtin_amdgcn_s_setprio(1);                 \
        MMAQ(0, 0, bf0);                               \
        __builtin_amdgcn_s_setprio(0);                 \
        WAIT_LGKM0();                                  \
        BARRIER();                                     \
        STG2(STAGE_A(s_, 0, (T) + 2);                  \
             STAGE_B(s_, 1, (T) + 2);)                 \
        __builtin_amdgcn_s_setprio(1);                 \
        MMAQ(0, 1, bf1);                               \
        __builtin_amdgcn_s_setprio(0);                 \
        LDA_HALF(s_, 1);                               \
        __builtin_amdgcn_s_setprio(1);                 \
        MMAQ(1, 1, bf1);                               \
        __builtin_amdgcn_s_setprio(0);                 \
        WAIT_LGKM0();                                  \
        BARRIER();                                     \
        STG2(STAGE_A(s_, 1, (T) + 2);)                 \
        __builtin_amdgcn_s_setprio(1);                 \
        MMAQ(1, 0, bf0);                               \
        __builtin_amdgcn_s_setprio(0);                 \
        VMOP;                                          \
        BARRIER();                                     \
        RDNEXT(LDA_HALF(s_ ^ 1, 0); LDB_HALF(s_ ^ 1, 0, bf0);) \
    }

__global__ __launch_bounds__(512, 2) void gemm256(const unsigned short* __restrict__ A, int lda,
                                                  const unsigned short* __restrict__ BT, int ldb,
                                                  const float* __restrict__ bias0,
                                                  const float* __restrict__ bias1, int nsplit,
                                                  unsigned short* __restrict__ C, int ldc,
                                                  int K, float s0, float s1, int gx) {
    __shared__ __align__(16) unsigned short Abuf[2][16384];  // 2 x 32KB
    __shared__ __align__(16) unsigned short Bbuf[2][16384];

    int nwg = gridDim.x, orig = blockIdx.x;
    int cpx = nwg >> 3;
    int wgid = (orig & 7) * cpx + (orig >> 3);
    int tm = wgid / gx, tn = wgid % gx;
    int m0 = tm * 256, n0 = tn * 256;

    int tid = threadIdx.x, lane = tid & 63, wid = tid >> 6;
    int wm = wid >> 2, wn = wid & 3;
    int lrow = lane & 15, lkg = lane >> 4;

    int t5 = tid >> 3;
    int cole = ((tid & 7) ^ ((tid >> 3) & 7)) << 3;
    const unsigned short* aS[2][2];
    const unsigned short* bS[2][2];
#pragma unroll
    for (int H = 0; H < 2; ++H)
#pragma unroll
        for (int c = 0; c < 2; ++c) {
            int rA = (c << 7) | (H << 6) | t5;
            int rB = (((c << 1) | (t5 >> 5)) << 6) | (H << 5) | (t5 & 31);
            aS[H][c] = A + (size_t)(m0 + rA) * lda + cole;
            bS[H][c] = BT + (size_t)(n0 + rB) * ldb + cole;
        }

    int xorc = (lkg * 8) ^ ((lrow & 7) << 3);
    int aoff = wm * 4096 + lrow * 64 + xorc;
    int boff = wn * 2048 + lrow * 64 + xorc;

    f32x4 acc[8][4];
#pragma unroll
    for (int i = 0; i < 8; ++i)
#pragma unroll
        for (int j = 0; j < 4; ++j) acc[i][j] = (f32x4){0.f, 0.f, 0.f, 0.f};
    bf16x8 af[4][2], bf0[2][2], bf1[2][2];

    const int nkt = K >> 6;

    // prologue: tile0 fully, tile1 {A0,B1,A1}; vmcnt(6) waits tile0's 8
    STAGE_A(0, 0, 0); STAGE_A(0, 1, 0); STAGE_B(0, 0, 0); STAGE_B(0, 1, 0);
    STAGE_A(1, 0, 1); STAGE_B(1, 1, 1); STAGE_A(1, 1, 1);
    VM6;
    BARRIER();
    LDA_HALF(0, 0);
    LDB_HALF(0, 0, bf0);  // R1(tile0)

    int t = 0;
    for (; t + 2 < nkt; ++t) KTILE_V2(t & 1, t, KEEP, KEEP, VM6, KEEP);
    KTILE_V2(t & 1, t, KEEP, DROP, VM0, KEEP);   // t=nkt-2: stage only (t+1).B0, drain
    ++t;
    KTILE_V2(t & 1, t, DROP, DROP, VMNONE, DROP);  // t=nkt-1: read-only

#pragma unroll
    for (int ni = 0; ni < 4; ++ni) {
        int col = n0 + wn * 64 + ni * 16 + lrow;
        float bval = (col < nsplit) ? bias0[col] : bias1[col - nsplit];
        float scl = (col < nsplit) ? s0 : s1;
#pragma unroll
        for (int mi = 0; mi < 8; ++mi) {
            int row = m0 + wm * 128 + mi * 16 + lkg * 4;
#pragma unroll
            for (int j = 0; j < 4; ++j)
                C[(size_t)(row + j) * ldc + col] = cvt_bf((acc[mi][ni][j] + bval) * scl);
        }
    }
}

// ================= 128x128 2-blocks/CU bf16 GEMM (GEMM2, unchanged) =================
#define STG128(S, KT)                                                                  \
    do {                                                                               \
        _Pragma("unroll") for (int i_ = 0; i_ < 4; ++i_)                               \
            GLDS16(Ag + (size_t)(i_ * 32) * lda + (size_t)(KT) * 64,                   \
                   &Abuf[S][i_ * 2048 + wid * 512]);                                   \
        _Pragma("unroll") for (int i_ = 0; i_ < 4; ++i_)                               \
            GLDS16(Bg + (size_t)(i_ * 32) * ldb + (size_t)(KT) * 64,                   \
                   &Bbuf[S][i_ * 2048 + wid * 512]);                                   \
    } while (0)

__global__ __launch_bounds__(256, 2) void gemm128(const unsigned short* __restrict__ A, int lda,
                                                  const unsigned short* __restrict__ BT, int ldb,
                                                  const float* __restrict__ bias0,
                                                  const float* __restrict__ bias1, int nsplit,
                                                  unsigned short* __restrict__ C, int ldc,
                                                  int K, float s0, float s1, int gy) {
    __shared__ __align__(16) unsigned short Abuf[2][8192];  // 2 x 16KB
    __shared__ __align__(16) unsigned short Bbuf[2][8192];

    int b = blockIdx.x;
    int tm = b % gy, tn = b / gy;
    int m0 = tm * 128, n0 = tn * 128;
    int tid = threadIdx.x, lane = tid & 63, wid = tid >> 6;
    int wm = wid >> 1, wn = wid & 1;
    int lrow = lane & 15, lkg = lane >> 4;

    int srow = tid >> 3;
    int cole = ((tid & 7) ^ ((tid >> 3) & 7)) << 3;
    const unsigned short* Ag = A + (size_t)(m0 + srow) * lda + cole;
    const unsigned short* Bg = BT + (size_t)(n0 + srow) * ldb + cole;

    int xorc8 = (lrow & 7) << 3;
    int aoff = (wm * 64 + lrow) * 64;
    int boff = (wn * 64 + lrow) * 64;

    f32x4 acc[4][4];
#pragma unroll
    for (int i = 0; i < 4; ++i)
#pragma unroll
        for (int j = 0; j < 4; ++j) acc[i][j] = (f32x4){0.f, 0.f, 0.f, 0.f};

    const int nkt = K >> 6;
    STG128(0, 0);
    for (int t = 0; t < nkt; ++t) {
        const int cur = t & 1;
        if (t + 1 < nkt) {
            STG128(cur ^ 1, t + 1);
            VM8;
        } else {
            VM0;
        }
        BARRIER();
        bf16x8 af[4][2], bv[4][2];
#pragma unroll
        for (int mi = 0; mi < 4; ++mi)
#pragma unroll
            for (int kh = 0; kh < 2; ++kh)
                af[mi][kh] = *(const bf16x8*)&Abuf[cur][aoff + mi * 1024 + (((kh * 4 + lkg) << 3) ^ xorc8)];
#pragma unroll
        for (int ni = 0; ni < 4; ++ni)
#pragma unroll
            for (int kh = 0; kh < 2; ++kh)
                bv[ni][kh] = *(const bf16x8*)&Bbuf[cur][boff + ni * 1024 + (((kh * 4 + lkg) << 3) ^ xorc8)];
        __builtin_amdgcn_s_setprio(1);
#pragma unroll
        for (int mi = 0; mi < 4; ++mi)
#pragma unroll
            for (int ni = 0; ni < 4; ++ni)
#pragma unroll
                for (int kh = 0; kh < 2; ++kh)
                    acc[mi][ni] = MFMA16(af[mi][kh], bv[ni][kh], acc[mi][ni]);
        __builtin_amdgcn_s_setprio(0);
        BARRIER();
    }

#pragma unroll
    for (int ni = 0; ni < 4; ++ni) {
        int col = n0 + wn * 64 + ni * 16 + lrow;
        float bval = (col < nsplit) ? bias0[col] : bias1[col - nsplit];
        float scl = (col < nsplit) ? s0 : s1;
#pragma unroll
        for (int mi = 0; mi < 4; ++mi) {
            int row = m0 + wm * 64 + mi * 16 + lkg * 4;
#pragma unroll
            for (int j = 0; j < 4; ++j)
                C[(size_t)(row + j) * ldc + col] = cvt_bf((acc[mi][ni][j] + bval) * scl);
        }
    }
}

// ---------------- flash attention (swapped QK^T, exp2, packed P, defer-max) ----------
__global__ __launch_bounds__(256) void attn(const unsigned short* __restrict__ q, int ldq,
                                            const unsigned short* __restrict__ k, int ldk,
                                            const unsigned short* __restrict__ v, int ldv,
                                            float* __restrict__ out) {
    const int S = 1024, D = 5120, Dh = 40;
    int b = blockIdx.z, h = blockIdx.y, qt = blockIdx.x;
    int t = threadIdx.x, lane = t & 63, wid = t >> 6;
    int lrow = lane & 15, lkg = lane >> 4;

    __shared__ __align__(16) unsigned short Ks[64 * 72];
    __shared__ __align__(16) unsigned short Vs[64 * 72];
    __shared__ __align__(16) unsigned short Ps[4][16 * 72];

    const size_t qbase = ((size_t)b * S) * ldq + (size_t)h * Dh;
    const size_t kbase = ((size_t)b * S) * ldk + (size_t)h * Dh;
    const size_t vbase = ((size_t)b * S) * ldv + (size_t)h * Dh;
    int q0 = qt * 64 + wid * 16;

    bf16x8 qf0, qf1;
    {
        const unsigned short* qp = q + qbase + (size_t)(q0 + lrow) * ldq;
        qf0 = *(const bf16x8*)(qp + lkg * 8);
        qf1 = (lkg == 0) ? *(const bf16x8*)(qp + 32) : bf8_zero();
    }

    f32x4 acc[3];
#pragma unroll
    for (int nb = 0; nb < 3; ++nb) acc[nb] = (f32x4){0.f, 0.f, 0.f, 0.f};
    float mrun = -INFINITY, lrun = 0.f;

    for (int kt = 0; kt < 16; ++kt) {
        __syncthreads();
#pragma unroll
        for (int it = 0; it < 2; ++it) {
            int idx = t + it * 256;
            int rr = idx >> 3, cc = idx & 7;
            uint4 val = make_uint4(0, 0, 0, 0);
            if (cc < 5) val = *(const uint4*)(k + kbase + (size_t)(kt * 64 + rr) * ldk + cc * 8);
            *(uint4*)&Ks[rr * 72 + cc * 8] = val;
        }
#pragma unroll
        for (int it = 0; it < 2; ++it) {
            int idx = t + it * 256;
            int rr = idx & 63, cc = idx >> 6;
            if (cc < 6) {
                uint4 val = make_uint4(0, 0, 0, 0);
                if (cc < 5) val = *(const uint4*)(v + vbase + (size_t)(kt * 64 + rr) * ldv + cc * 8);
                const unsigned short* pv = (const unsigned short*)&val;
#pragma unroll
                for (int j = 0; j < 8; ++j) Vs[(cc * 8 + j) * 72 + rr] = pv[j];
            }
        }
        __syncthreads();

        f32x4 sf[4];
#pragma unroll
        for (int nb = 0; nb < 4; ++nb) {
            sf[nb] = (f32x4){0.f, 0.f, 0.f, 0.f};
            bf16x8 kf0 = *(const bf16x8*)&Ks[(nb * 16 + lrow) * 72 + lkg * 8];
            bf16x8 kf1 = *(const bf16x8*)&Ks[(nb * 16 + lrow) * 72 + 32 + lkg * 8];
            sf[nb] = MFMA16(kf0, qf0, sf[nb]);
            sf[nb] = MFMA16(kf1, qf1, sf[nb]);
        }

        float tm = sf[0][0];
#pragma unroll
        for (int nb = 0; nb < 4; ++nb)
#pragma unroll
            for (int i = 0; i < 4; ++i) tm = fmaxf(tm, sf[nb][i]);
        tm = fmaxf(tm, __shfl_xor(tm, 16));
        tm = fmaxf(tm, __shfl_xor(tm, 32));

        // defer-max (T13): skip the O-rescale when max grew < 11 (log2 units; P<=2^11)
        float mn = mrun, al = 1.0f;
        bool resc = !__all(tm <= mrun + 11.0f);
        if (resc) {
            mn = fmaxf(mrun, tm);
            al = EXP2F(mrun - mn);
            mrun = mn;
        }
        float rs = 0.f;
#pragma unroll
        for (int nb = 0; nb < 4; ++nb) {
            bf16x4 pk;
#pragma unroll
            for (int i = 0; i < 4; ++i) {
                float p = EXP2F(sf[nb][i] - mn);
                rs += p;
                pk[i] = (__bf16)p;
            }
            *(bf16x4*)&Ps[wid][lrow * 72 + nb * 16 + lkg * 4] = pk;
        }
        rs += __shfl_xor(rs, 16);
        rs += __shfl_xor(rs, 32);
        lrun = lrun * al + rs;

        if (resc) {
            float alr[4];
#pragma unroll
            for (int i = 0; i < 4; ++i) alr[i] = __shfl(al, lkg * 4 + i);
#pragma unroll
            for (int nb = 0; nb < 3; ++nb)
#pragma unroll
                for (int i = 0; i < 4; ++i) acc[nb][i] *= alr[i];
        }

#pragma unroll
        for (int kk = 0; kk < 2; ++kk) {
            bf16x8 pf = *(const bf16x8*)&Ps[wid][lrow * 72 + kk * 32 + lkg * 8];
#pragma unroll
            for (int nb = 0; nb < 3; ++nb) {
                bf16x8 vf = *(const bf16x8*)&Vs[(nb * 16 + lrow) * 72 + kk * 32 + lkg * 8];
                acc[nb] = MFMA16(pf, vf, acc[nb]);
            }
        }
    }

    float lr[4];
#pragma unroll
    for (int i = 0; i < 4; ++i) lr[i] = __shfl(lrun, lkg * 4 + i);
#pragma unroll
    for (int i = 0; i < 4; ++i) {
        float inv = 1.0f / lr[i];
        int s = q0 + lkg * 4 + i;
#pragma unroll
        for (int nb = 0; nb < 3; ++nb) {
            int d = nb * 16 + lrow;
            if (d < Dh) out[((size_t)(b * S + s)) * D + h * Dh + d] = acc[nb][i] * inv;
        }
    }
}

extern "C" void kernel_launch(void* const* d_in, const int* in_sizes, int n_in,
                              void* d_out, int out_size, void* d_ws, size_t ws_size,
                              hipStream_t stream) {
    const int M = 2048, D = 5120, L = 1536, NQ = D + L /*6656*/, NKV = 2 * D /*10240*/;
    const float* x  = (const float*)d_in[0];
    const float* Wq = (const float*)d_in[1];
    const float* bq = (const float*)d_in[2];
    const float* Wc = (const float*)d_in[3];
    const float* bc = (const float*)d_in[4];
    const float* Wk = (const float*)d_in[5];
    const float* bk = (const float*)d_in[6];
    const float* Wv = (const float*)d_in[7];
    const float* bv = (const float*)d_in[8];
    float* out = (float*)d_out;

    unsigned short* ws = (unsigned short*)d_ws;
    size_t off = 0;
    unsigned short* xb    = ws + off; off += (size_t)M * D;
    unsigned short* WqcT  = ws + off; off += (size_t)NQ * D;   // [Wq|Wc]^T : [6656][5120]
    unsigned short* WkvT  = ws + off; off += (size_t)NKV * L;  // [Wk|Wv]^T : [10240][1536]
    unsigned short* qkvb  = ws + off; off += (size_t)M * NQ;   // [q | kv_latent]
    unsigned short* kvout = ws + off; off += (size_t)M * NKV;  // [k | v]

    xconv<<<(M * D) / 1024, 256, 0, stream>>>(x, xb, M * D);
    wconv<<<dim3(D / 32, D / 32), 256, 0, stream>>>(Wq, WqcT, D, D);
    wconv<<<dim3(L / 32, D / 32), 256, 0, stream>>>(Wc, WqcT + (size_t)D * D, D, L);
    wconv<<<dim3(D / 32, L / 32), 256, 0, stream>>>(Wk, WkvT, L, D);
    wconv<<<dim3(D / 32, L / 32), 256, 0, stream>>>(Wv, WkvT + (size_t)D * L, L, D);

    const float qscale = 1.4426950408889634f / 6.324555320336759f;  // log2(e)/sqrt(40)

    // GEMM1: [q | kv_latent] = x @ [Wq | Wc]   grid 208 (8x26), 256^2 pipelined
    gemm256<<<dim3((NQ / 256) * (M / 256)), 512, 0, stream>>>(xb, D, WqcT, D, bq, bc, D,
                                                              qkvb, NQ, D, qscale, 1.0f,
                                                              NQ / 256);
    // GEMM2: [k | v] = kv_latent @ [Wk | Wv]   grid 1280 (80x16), 128^2 2-blocks/CU
    gemm128<<<dim3((NKV / 128) * (M / 128)), 256, 0, stream>>>(qkvb + D, NQ, WkvT, L, bk, bv, D,
                                                               kvout, NKV, L, 1.0f, 1.0f,
                                                               M / 128);

    attn<<<dim3(1024 / 64, 128, 2), 256, 0, stream>>>(qkvb, NQ, kvout, NKV, kvout + D, NKV, out);
}

// Round 7
// 470.694 us; speedup vs baseline: 1.5098x; 1.0415x over previous
//
#include <hip/hip_runtime.h>
#include <hip/hip_bf16.h>

typedef __attribute__((ext_vector_type(8))) __bf16 bf16x8;
typedef __attribute__((ext_vector_type(4))) __bf16 bf16x4;
typedef __attribute__((ext_vector_type(4))) float f32x4;

#define MFMA16(a, b, c) __builtin_amdgcn_mfma_f32_16x16x32_bf16((a), (b), (c), 0, 0, 0)

#if __has_builtin(__builtin_amdgcn_exp2f)
#define EXP2F(x) __builtin_amdgcn_exp2f(x)
#else
#define EXP2F(x) exp2f(x)
#endif

#define GLDS16(g, l)                                                             \
    __builtin_amdgcn_global_load_lds((const __attribute__((address_space(1))) void*)(g), \
                                     (__attribute__((address_space(3))) void*)(l), 16, 0, 0)

#define BARRIER()                          \
    do {                                   \
        asm volatile("" ::: "memory");     \
        __builtin_amdgcn_s_barrier();      \
        asm volatile("" ::: "memory");     \
    } while (0)

#define WAIT_LGKM0() asm volatile("s_waitcnt lgkmcnt(0)" ::: "memory")
#define VM6 asm volatile("s_waitcnt vmcnt(6)" ::: "memory")
#define VM8 asm volatile("s_waitcnt vmcnt(8)" ::: "memory")
#define VM0 asm volatile("s_waitcnt vmcnt(0)" ::: "memory")
#define VMNONE ((void)0)
#define KEEP(x) x
#define DROP(x)

static __device__ __forceinline__ unsigned short cvt_bf(float f) {
    return __builtin_bit_cast(unsigned short, (__bf16)f);
}

static __device__ __forceinline__ bf16x8 bf8_zero() {
    uint4 z = make_uint4(0, 0, 0, 0);
    return __builtin_bit_cast(bf16x8, z);
}

// ---------------- fp32 -> bf16 elementwise (x) ----------------
__global__ __launch_bounds__(256) void xconv(const float* __restrict__ X,
                                             unsigned short* __restrict__ Xb, int n) {
    int i = (blockIdx.x * 256 + threadIdx.x) * 4;
    if (i < n) {
        float4 f = *(const float4*)(X + i);
        ushort4 o;
        o.x = cvt_bf(f.x); o.y = cvt_bf(f.y); o.z = cvt_bf(f.z); o.w = cvt_bf(f.w);
        *(ushort4*)(Xb + i) = o;
    }
}

// ---------------- fp32 W[K][N] -> bf16 WT[N][K], all 4 weights in 1 launch ----------
__global__ __launch_bounds__(256) void wconv4(const float* __restrict__ Wq,
                                              const float* __restrict__ Wc,
                                              const float* __restrict__ Wk,
                                              const float* __restrict__ Wv,
                                              unsigned short* __restrict__ dqc,
                                              unsigned short* __restrict__ dkv) {
    const int D = 5120, L = 1536;
    int b = blockIdx.x;
    const float* W;
    unsigned short* WT;
    int K, N;
    if (b < 25600) { W = Wq; WT = dqc; K = D; N = D; }
    else if (b < 33280) { b -= 25600; W = Wc; WT = dqc + (size_t)D * D; K = D; N = L; }
    else if (b < 40960) { b -= 33280; W = Wk; WT = dkv; K = L; N = D; }
    else { b -= 40960; W = Wv; WT = dkv + (size_t)D * L; K = L; N = D; }
    int nx = N / 32;
    int n0 = (b % nx) * 32, k0 = (b / nx) * 32;

    __shared__ unsigned short tile[32][33];  // [k][n]
    int c = threadIdx.x & 31, r8 = threadIdx.x >> 5;
#pragma unroll
    for (int it = 0; it < 4; ++it) {
        int r = r8 + it * 8;
        tile[r][c] = cvt_bf(W[(size_t)(k0 + r) * N + n0 + c]);
    }
    __syncthreads();
    int k2 = (threadIdx.x & 15) * 2, n8 = threadIdx.x >> 4;
#pragma unroll
    for (int it = 0; it < 2; ++it) {
        int n = n8 + it * 16;
        ushort2 o;
        o.x = tile[k2][n];
        o.y = tile[k2 + 1][n];
        *(ushort2*)&WT[(size_t)(n0 + n) * K + k0 + k2] = o;
    }
}

// ================= 256x256 pipelined bf16 GEMM (control, unchanged) ======
#define STAGE_A(S, H, KT)                                                              \
    do {                                                                               \
        GLDS16(aS[H][0] + (size_t)(KT) * 64, &Abuf[S][(H) * 8192 + wid * 512]);        \
        GLDS16(aS[H][1] + (size_t)(KT) * 64, &Abuf[S][(H) * 8192 + 4096 + wid * 512]); \
    } while (0)
#define STAGE_B(S, H, KT)                                                              \
    do {                                                                               \
        GLDS16(bS[H][0] + (size_t)(KT) * 64, &Bbuf[S][(H) * 8192 + wid * 512]);        \
        GLDS16(bS[H][1] + (size_t)(KT) * 64, &Bbuf[S][(H) * 8192 + 4096 + wid * 512]); \
    } while (0)

#define LDA_HALF(S, QM)                                                                   \
    do {                                                                                  \
        _Pragma("unroll") for (int mi = 0; mi < 4; ++mi)                                  \
            _Pragma("unroll") for (int kh = 0; kh < 2; ++kh)                              \
                af[mi][kh] =                                                              \
                    *(const bf16x8*)&Abuf[S][((QM) * 8192 + aoff + mi * 1024) ^ (kh * 32)]; \
    } while (0)
#define LDB_HALF(S, QN, BF)                                                               \
    do {                                                                                  \
        _Pragma("unroll") for (int ni = 0; ni < 2; ++ni)                                  \
            _Pragma("unroll") for (int kh = 0; kh < 2; ++kh)                              \
                BF[ni][kh] =                                                              \
                    *(const bf16x8*)&Bbuf[S][((QN) * 8192 + boff + ni * 1024) ^ (kh * 32)]; \
    } while (0)

#define MMAQ(QM, QN, BF)                                                                \
    do {                                                                                \
        _Pragma("unroll") for (int mi = 0; mi < 4; ++mi)                                \
            _Pragma("unroll") for (int ni = 0; ni < 2; ++ni)                            \
                _Pragma("unroll") for (int kh = 0; kh < 2; ++kh)                        \
                    acc[(QM) * 4 + mi][(QN) * 2 + ni] =                                 \
                        MFMA16(af[mi][kh], BF[ni][kh], acc[(QM) * 4 + mi][(QN) * 2 + ni]); \
    } while (0)

#define KTILE_V2(S, T, STG1, STG2, VMOP, RDNEXT)       \
    {                                                  \
        const int s_ = (S);                            \
        LDB_HALF(s_, 1, bf1);                          \
        STG1(STAGE_B(s_ ^ 1, 0, (T) + 1);)             \
        __builtin_amdgcn_s_setprio(1);                 \
        MMAQ(0, 0, bf0);                               \
        __builtin_amdgcn_s_setprio(0);                 \
        WAIT_LGKM0();                                  \
        BARRIER();                                     \
        STG2(STAGE_A(s_, 0, (T) + 2);                  \
             STAGE_B(s_, 1, (T) + 2);)                 \
        __builtin_amdgcn_s_setprio(1);                 \
        MMAQ(0, 1, bf1);                               \
        __builtin_amdgcn_s_setprio(0);                 \
        LDA_HALF(s_, 1);                               \
        __builtin_amdgcn_s_setprio(1);                 \
        MMAQ(1, 1, bf1);                               \
        __builtin_amdgcn_s_setprio(0);                 \
        WAIT_LGKM0();                                  \
        BARRIER();                                     \
        STG2(STAGE_A(s_, 1, (T) + 2);)                 \
        __builtin_amdgcn_s_setprio(1);                 \
        MMAQ(1, 0, bf0);                               \
        __builtin_amdgcn_s_setprio(0);                 \
        VMOP;                                          \
        BARRIER();                                     \
        RDNEXT(LDA_HALF(s_ ^ 1, 0); LDB_HALF(s_ ^ 1, 0, bf0);) \
    }

__global__ __launch_bounds__(512, 2) void gemm256(const unsigned short* __restrict__ A, int lda,
                                                  const unsigned short* __restrict__ BT, int ldb,
                                                  const float* __restrict__ bias0,
                                                  const float* __restrict__ bias1, int nsplit,
                                                  unsigned short* __restrict__ C, int ldc,
                                                  int K, float s0, float s1, int gx) {
    __shared__ __align__(16) unsigned short Abuf[2][16384];  // 2 x 32KB
    __shared__ __align__(16) unsigned short Bbuf[2][16384];

    int nwg = gridDim.x, orig = blockIdx.x;
    int cpx = nwg >> 3;
    int wgid = (orig & 7) * cpx + (orig >> 3);
    int tm = wgid / gx, tn = wgid % gx;
    int m0 = tm * 256, n0 = tn * 256;

    int tid = threadIdx.x, lane = tid & 63, wid = tid >> 6;
    int wm = wid >> 2, wn = wid & 3;
    int lrow = lane & 15, lkg = lane >> 4;

    int t5 = tid >> 3;
    int cole = ((tid & 7) ^ ((tid >> 3) & 7)) << 3;
    const unsigned short* aS[2][2];
    const unsigned short* bS[2][2];
#pragma unroll
    for (int H = 0; H < 2; ++H)
#pragma unroll
        for (int c = 0; c < 2; ++c) {
            int rA = (c << 7) | (H << 6) | t5;
            int rB = (((c << 1) | (t5 >> 5)) << 6) | (H << 5) | (t5 & 31);
            aS[H][c] = A + (size_t)(m0 + rA) * lda + cole;
            bS[H][c] = BT + (size_t)(n0 + rB) * ldb + cole;
        }

    int xorc = (lkg * 8) ^ ((lrow & 7) << 3);
    int aoff = wm * 4096 + lrow * 64 + xorc;
    int boff = wn * 2048 + lrow * 64 + xorc;

    f32x4 acc[8][4];
#pragma unroll
    for (int i = 0; i < 8; ++i)
#pragma unroll
        for (int j = 0; j < 4; ++j) acc[i][j] = (f32x4){0.f, 0.f, 0.f, 0.f};
    bf16x8 af[4][2], bf0[2][2], bf1[2][2];

    const int nkt = K >> 6;

    STAGE_A(0, 0, 0); STAGE_A(0, 1, 0); STAGE_B(0, 0, 0); STAGE_B(0, 1, 0);
    STAGE_A(1, 0, 1); STAGE_B(1, 1, 1); STAGE_A(1, 1, 1);
    VM6;
    BARRIER();
    LDA_HALF(0, 0);
    LDB_HALF(0, 0, bf0);

    int t = 0;
    for (; t + 2 < nkt; ++t) KTILE_V2(t & 1, t, KEEP, KEEP, VM6, KEEP);
    KTILE_V2(t & 1, t, KEEP, DROP, VM0, KEEP);
    ++t;
    KTILE_V2(t & 1, t, DROP, DROP, VMNONE, DROP);

#pragma unroll
    for (int ni = 0; ni < 4; ++ni) {
        int col = n0 + wn * 64 + ni * 16 + lrow;
        float bval = (col < nsplit) ? bias0[col] : bias1[col - nsplit];
        float scl = (col < nsplit) ? s0 : s1;
#pragma unroll
        for (int mi = 0; mi < 8; ++mi) {
            int row = m0 + wm * 128 + mi * 16 + lkg * 4;
#pragma unroll
            for (int j = 0; j < 4; ++j)
                C[(size_t)(row + j) * ldc + col] = cvt_bf((acc[mi][ni][j] + bval) * scl);
        }
    }
}

// ================= 128x128 2-blocks/CU bf16 GEMM (GEMM2, unchanged) =================
#define STG128(S, KT)                                                                  \
    do {                                                                               \
        _Pragma("unroll") for (int i_ = 0; i_ < 4; ++i_)                               \
            GLDS16(Ag + (size_t)(i_ * 32) * lda + (size_t)(KT) * 64,                   \
                   &Abuf[S][i_ * 2048 + wid * 512]);                                   \
        _Pragma("unroll") for (int i_ = 0; i_ < 4; ++i_)                               \
            GLDS16(Bg + (size_t)(i_ * 32) * ldb + (size_t)(KT) * 64,                   \
                   &Bbuf[S][i_ * 2048 + wid * 512]);                                   \
    } while (0)

__global__ __launch_bounds__(256, 2) void gemm128(const unsigned short* __restrict__ A, int lda,
                                                  const unsigned short* __restrict__ BT, int ldb,
                                                  const float* __restrict__ bias0,
                                                  const float* __restrict__ bias1, int nsplit,
                                                  unsigned short* __restrict__ C, int ldc,
                                                  int K, float s0, float s1, int gy) {
    __shared__ __align__(16) unsigned short Abuf[2][8192];  // 2 x 16KB
    __shared__ __align__(16) unsigned short Bbuf[2][8192];

    int b = blockIdx.x;
    int tm = b % gy, tn = b / gy;
    int m0 = tm * 128, n0 = tn * 128;
    int tid = threadIdx.x, lane = tid & 63, wid = tid >> 6;
    int wm = wid >> 1, wn = wid & 1;
    int lrow = lane & 15, lkg = lane >> 4;

    int srow = tid >> 3;
    int cole = ((tid & 7) ^ ((tid >> 3) & 7)) << 3;
    const unsigned short* Ag = A + (size_t)(m0 + srow) * lda + cole;
    const unsigned short* Bg = BT + (size_t)(n0 + srow) * ldb + cole;

    int xorc8 = (lrow & 7) << 3;
    int aoff = (wm * 64 + lrow) * 64;
    int boff = (wn * 64 + lrow) * 64;

    f32x4 acc[4][4];
#pragma unroll
    for (int i = 0; i < 4; ++i)
#pragma unroll
        for (int j = 0; j < 4; ++j) acc[i][j] = (f32x4){0.f, 0.f, 0.f, 0.f};

    const int nkt = K >> 6;
    STG128(0, 0);
    for (int t = 0; t < nkt; ++t) {
        const int cur = t & 1;
        if (t + 1 < nkt) {
            STG128(cur ^ 1, t + 1);
            VM8;
        } else {
            VM0;
        }
        BARRIER();
        bf16x8 af[4][2], bv[4][2];
#pragma unroll
        for (int mi = 0; mi < 4; ++mi)
#pragma unroll
            for (int kh = 0; kh < 2; ++kh)
                af[mi][kh] = *(const bf16x8*)&Abuf[cur][aoff + mi * 1024 + (((kh * 4 + lkg) << 3) ^ xorc8)];
#pragma unroll
        for (int ni = 0; ni < 4; ++ni)
#pragma unroll
            for (int kh = 0; kh < 2; ++kh)
                bv[ni][kh] = *(const bf16x8*)&Bbuf[cur][boff + ni * 1024 + (((kh * 4 + lkg) << 3) ^ xorc8)];
        __builtin_amdgcn_s_setprio(1);
#pragma unroll
        for (int mi = 0; mi < 4; ++mi)
#pragma unroll
            for (int ni = 0; ni < 4; ++ni)
#pragma unroll
                for (int kh = 0; kh < 2; ++kh)
                    acc[mi][ni] = MFMA16(af[mi][kh], bv[ni][kh], acc[mi][ni]);
        __builtin_amdgcn_s_setprio(0);
        BARRIER();
    }

#pragma unroll
    for (int ni = 0; ni < 4; ++ni) {
        int col = n0 + wn * 64 + ni * 16 + lrow;
        float bval = (col < nsplit) ? bias0[col] : bias1[col - nsplit];
        float scl = (col < nsplit) ? s0 : s1;
#pragma unroll
        for (int mi = 0; mi < 4; ++mi) {
            int row = m0 + wm * 64 + mi * 16 + lkg * 4;
#pragma unroll
            for (int j = 0; j < 4; ++j)
                C[(size_t)(row + j) * ldc + col] = cvt_bf((acc[mi][ni][j] + bval) * scl);
        }
    }
}

// ---------------- flash attention (pipelined staging + setprio + defer-max) ----------
// grid (S/64, H, B); block 256 = 4 waves x 16 q-rows; 16 KV tiles of 64.
// Staging split: tile kt+1's global loads issue right after the compute barrier
// (complete under compute of kt); next iteration writes regs -> LDS only.
__global__ __launch_bounds__(256) void attn(const unsigned short* __restrict__ q, int ldq,
                                            const unsigned short* __restrict__ k, int ldk,
                                            const unsigned short* __restrict__ v, int ldv,
                                            float* __restrict__ out) {
    const int S = 1024, D = 5120, Dh = 40;
    int b = blockIdx.z, h = blockIdx.y, qt = blockIdx.x;
    int t = threadIdx.x, lane = t & 63, wid = t >> 6;
    int lrow = lane & 15, lkg = lane >> 4;

    __shared__ __align__(16) unsigned short Ks[64 * 72];
    __shared__ __align__(16) unsigned short Vs[64 * 72];
    __shared__ __align__(16) unsigned short Ps[4][16 * 72];

    const size_t qbase = ((size_t)b * S) * ldq + (size_t)h * Dh;
    int q0 = qt * 64 + wid * 16;

    bf16x8 qf0, qf1;
    {
        const unsigned short* qp = q + qbase + (size_t)(q0 + lrow) * ldq;
        qf0 = *(const bf16x8*)(qp + lkg * 8);
        qf1 = (lkg == 0) ? *(const bf16x8*)(qp + 32) : bf8_zero();
    }

    // staging descriptors
    int rrK = t >> 3, ccK = t & 7;           // K: rows rrK, rrK+32; valid iff ccK<5
    int rrV = t & 63, ccV = t >> 6;          // V: cc ccV and ccV+4 (load iff ccV==0)
    const unsigned short* kp = k + ((size_t)b * S) * ldk + (size_t)h * Dh +
                               (size_t)rrK * ldk + ccK * 8;
    const unsigned short* vp = v + ((size_t)b * S) * ldv + (size_t)h * Dh +
                               (size_t)rrV * ldv + ccV * 8;
    const size_t kstep = (size_t)64 * ldk, vstep = (size_t)64 * ldv;

    uint4 kv0, kv1, vv0, vv1;
    kv0 = kv1 = vv0 = vv1 = make_uint4(0, 0, 0, 0);
    // preload kt = 0
    if (ccK < 5) { kv0 = *(const uint4*)kp; kv1 = *(const uint4*)(kp + 32 * ldk); }
    vv0 = *(const uint4*)vp;
    if (ccV == 0) vv1 = *(const uint4*)(vp + 32);
    kp += kstep; vp += vstep;

    f32x4 acc[3];
#pragma unroll
    for (int nb = 0; nb < 3; ++nb) acc[nb] = (f32x4){0.f, 0.f, 0.f, 0.f};
    float mrun = -INFINITY, lrun = 0.f;

    for (int kt = 0; kt < 16; ++kt) {
        __syncthreads();  // everyone done reading LDS from previous tile
        // write K tile (zeros for ccK>=5)
        uint4 w0 = (ccK < 5) ? kv0 : make_uint4(0, 0, 0, 0);
        uint4 w1 = (ccK < 5) ? kv1 : make_uint4(0, 0, 0, 0);
        *(uint4*)&Ks[rrK * 72 + ccK * 8] = w0;
        *(uint4*)&Ks[(rrK + 32) * 72 + ccK * 8] = w1;
        // write V transposed: cols ccV*8.. and (ccV+4)*8.. ; rows 40..47 zeroed
        {
            const unsigned short* pv = (const unsigned short*)&vv0;
#pragma unroll
            for (int j = 0; j < 8; ++j) Vs[(ccV * 8 + j) * 72 + rrV] = pv[j];
            if (ccV < 2) {
                uint4 z = (ccV == 0) ? vv1 : make_uint4(0, 0, 0, 0);
                const unsigned short* pz = (const unsigned short*)&z;
#pragma unroll
                for (int j = 0; j < 8; ++j) Vs[((ccV + 4) * 8 + j) * 72 + rrV] = pz[j];
            }
        }
        __syncthreads();
        // issue next tile's loads; they complete under this tile's compute
        if (kt + 1 < 16) {
            if (ccK < 5) { kv0 = *(const uint4*)kp; kv1 = *(const uint4*)(kp + 32 * ldk); }
            vv0 = *(const uint4*)vp;
            if (ccV == 0) vv1 = *(const uint4*)(vp + 32);
            kp += kstep; vp += vstep;
        }

        f32x4 sf[4];
        __builtin_amdgcn_s_setprio(1);
#pragma unroll
        for (int nb = 0; nb < 4; ++nb) {
            sf[nb] = (f32x4){0.f, 0.f, 0.f, 0.f};
            bf16x8 kf0 = *(const bf16x8*)&Ks[(nb * 16 + lrow) * 72 + lkg * 8];
            bf16x8 kf1 = *(const bf16x8*)&Ks[(nb * 16 + lrow) * 72 + 32 + lkg * 8];
            sf[nb] = MFMA16(kf0, qf0, sf[nb]);
            sf[nb] = MFMA16(kf1, qf1, sf[nb]);
        }
        __builtin_amdgcn_s_setprio(0);

        float tm = sf[0][0];
#pragma unroll
        for (int nb = 0; nb < 4; ++nb)
#pragma unroll
            for (int i = 0; i < 4; ++i) tm = fmaxf(tm, sf[nb][i]);
        tm = fmaxf(tm, __shfl_xor(tm, 16));
        tm = fmaxf(tm, __shfl_xor(tm, 32));

        // defer-max (T13): skip O-rescale while max growth < 11 (log2 units)
        float mn = mrun, al = 1.0f;
        bool resc = !__all(tm <= mrun + 11.0f);
        if (resc) {
            mn = fmaxf(mrun, tm);
            al = EXP2F(mrun - mn);
            mrun = mn;
        }
        float rs = 0.f;
#pragma unroll
        for (int nb = 0; nb < 4; ++nb) {
            bf16x4 pk;
#pragma unroll
            for (int i = 0; i < 4; ++i) {
                float p = EXP2F(sf[nb][i] - mn);
                rs += p;
                pk[i] = (__bf16)p;
            }
            *(bf16x4*)&Ps[wid][lrow * 72 + nb * 16 + lkg * 4] = pk;
        }
        rs += __shfl_xor(rs, 16);
        rs += __shfl_xor(rs, 32);
        lrun = lrun * al + rs;

        if (resc) {
            float alr[4];
#pragma unroll
            for (int i = 0; i < 4; ++i) alr[i] = __shfl(al, lkg * 4 + i);
#pragma unroll
            for (int nb = 0; nb < 3; ++nb)
#pragma unroll
                for (int i = 0; i < 4; ++i) acc[nb][i] *= alr[i];
        }

        __builtin_amdgcn_s_setprio(1);
#pragma unroll
        for (int kk = 0; kk < 2; ++kk) {
            bf16x8 pf = *(const bf16x8*)&Ps[wid][lrow * 72 + kk * 32 + lkg * 8];
#pragma unroll
            for (int nb = 0; nb < 3; ++nb) {
                bf16x8 vf = *(const bf16x8*)&Vs[(nb * 16 + lrow) * 72 + kk * 32 + lkg * 8];
                acc[nb] = MFMA16(pf, vf, acc[nb]);
            }
        }
        __builtin_amdgcn_s_setprio(0);
    }

    float lr[4];
#pragma unroll
    for (int i = 0; i < 4; ++i) lr[i] = __shfl(lrun, lkg * 4 + i);
#pragma unroll
    for (int i = 0; i < 4; ++i) {
        float inv = 1.0f / lr[i];
        int s = q0 + lkg * 4 + i;
#pragma unroll
        for (int nb = 0; nb < 3; ++nb) {
            int d = nb * 16 + lrow;
            if (d < Dh) out[((size_t)(b * S + s)) * D + h * Dh + d] = acc[nb][i] * inv;
        }
    }
}

extern "C" void kernel_launch(void* const* d_in, const int* in_sizes, int n_in,
                              void* d_out, int out_size, void* d_ws, size_t ws_size,
                              hipStream_t stream) {
    const int M = 2048, D = 5120, L = 1536, NQ = D + L /*6656*/, NKV = 2 * D /*10240*/;
    const float* x  = (const float*)d_in[0];
    const float* Wq = (const float*)d_in[1];
    const float* bq = (const float*)d_in[2];
    const float* Wc = (const float*)d_in[3];
    const float* bc = (const float*)d_in[4];
    const float* Wk = (const float*)d_in[5];
    const float* bk = (const float*)d_in[6];
    const float* Wv = (const float*)d_in[7];
    const float* bv = (const float*)d_in[8];
    float* out = (float*)d_out;

    unsigned short* ws = (unsigned short*)d_ws;
    size_t off = 0;
    unsigned short* xb    = ws + off; off += (size_t)M * D;
    unsigned short* WqcT  = ws + off; off += (size_t)NQ * D;   // [Wq|Wc]^T : [6656][5120]
    unsigned short* WkvT  = ws + off; off += (size_t)NKV * L;  // [Wk|Wv]^T : [10240][1536]
    unsigned short* qkvb  = ws + off; off += (size_t)M * NQ;   // [q | kv_latent]
    unsigned short* kvout = ws + off; off += (size_t)M * NKV;  // [k | v]

    xconv<<<(M * D) / 1024, 256, 0, stream>>>(x, xb, M * D);
    // all 4 weight transposes in one launch: 25600 + 7680 + 7680 + 7680 = 48640 blocks
    wconv4<<<48640, 256, 0, stream>>>(Wq, Wc, Wk, Wv, WqcT, WkvT);

    const float qscale = 1.4426950408889634f / 6.324555320336759f;  // log2(e)/sqrt(40)

    // GEMM1: [q | kv_latent] = x @ [Wq | Wc]   grid 208 (8x26), 256^2 pipelined
    gemm256<<<dim3((NQ / 256) * (M / 256)), 512, 0, stream>>>(xb, D, WqcT, D, bq, bc, D,
                                                              qkvb, NQ, D, qscale, 1.0f,
                                                              NQ / 256);
    // GEMM2: [k | v] = kv_latent @ [Wk | Wv]   grid 1280 (80x16), 128^2 2-blocks/CU
    gemm128<<<dim3((NKV / 128) * (M / 128)), 256, 0, stream>>>(qkvb + D, NQ, WkvT, L, bk, bv, D,
                                                               kvout, NKV, L, 1.0f, 1.0f,
                                                               M / 128);

    attn<<<dim3(1024 / 64, 128, 2), 256, 0, stream>>>(qkvb, NQ, kvout, NKV, kvout + D, NKV, out);
}

// Round 8
// 465.956 us; speedup vs baseline: 1.5252x; 1.0102x over previous
//
#include <hip/hip_runtime.h>
#include <hip/hip_bf16.h>

typedef __attribute__((ext_vector_type(8))) __bf16 bf16x8;
typedef __attribute__((ext_vector_type(4))) __bf16 bf16x4;
typedef __attribute__((ext_vector_type(4))) float f32x4;

#define MFMA16(a, b, c) __builtin_amdgcn_mfma_f32_16x16x32_bf16((a), (b), (c), 0, 0, 0)

#if __has_builtin(__builtin_amdgcn_exp2f)
#define EXP2F(x) __builtin_amdgcn_exp2f(x)
#else
#define EXP2F(x) exp2f(x)
#endif

#define GLDS16(g, l)                                                             \
    __builtin_amdgcn_global_load_lds((const __attribute__((address_space(1))) void*)(g), \
                                     (__attribute__((address_space(3))) void*)(l), 16, 0, 0)

#define BARRIER()                          \
    do {                                   \
        asm volatile("" ::: "memory");     \
        __builtin_amdgcn_s_barrier();      \
        asm volatile("" ::: "memory");     \
    } while (0)

#define WAIT_LGKM0() asm volatile("s_waitcnt lgkmcnt(0)" ::: "memory")
#define VM6 asm volatile("s_waitcnt vmcnt(6)" ::: "memory")
#define VM8 asm volatile("s_waitcnt vmcnt(8)" ::: "memory")
#define VM0 asm volatile("s_waitcnt vmcnt(0)" ::: "memory")
#define VMNONE ((void)0)
#define KEEP(x) x
#define DROP(x)

static __device__ __forceinline__ unsigned short cvt_bf(float f) {
    return __builtin_bit_cast(unsigned short, (__bf16)f);
}

static __device__ __forceinline__ bf16x8 bf8_zero() {
    uint4 z = make_uint4(0, 0, 0, 0);
    return __builtin_bit_cast(bf16x8, z);
}

// ---------------- prep: x fp32->bf16 + all 4 weight transposes, ONE launch ----------
// x part: 8 elems/thread (2x float4 -> uint4 store).
// W part: 64x64 tiles; float4 coalesced loads, LDS [64][65] (2-way banks max),
// uint4 (8x bf16) coalesced stores of WT[n][k].
__global__ __launch_bounds__(256) void prep(const float* __restrict__ X,
                                            const float* __restrict__ Wq,
                                            const float* __restrict__ Wc,
                                            const float* __restrict__ Wk,
                                            const float* __restrict__ Wv,
                                            unsigned short* __restrict__ Xb,
                                            unsigned short* __restrict__ dqc,
                                            unsigned short* __restrict__ dkv) {
    const int D = 5120, L = 1536;
    int b = blockIdx.x, t = threadIdx.x;
    if (b < 5120) {  // xconv: 5120 blocks cover 2048*5120 elems
        int i = (b * 256 + t) * 8;
        float4 f0 = *(const float4*)(X + i);
        float4 f1 = *(const float4*)(X + i + 4);
        unsigned short o[8];
        o[0] = cvt_bf(f0.x); o[1] = cvt_bf(f0.y); o[2] = cvt_bf(f0.z); o[3] = cvt_bf(f0.w);
        o[4] = cvt_bf(f1.x); o[5] = cvt_bf(f1.y); o[6] = cvt_bf(f1.z); o[7] = cvt_bf(f1.w);
        *(uint4*)(Xb + i) = *(const uint4*)o;
        return;
    }
    int b2 = b - 5120;
    const float* W;
    unsigned short* WT;
    int K, N;
    if (b2 < 6400) { W = Wq; WT = dqc; K = D; N = D; }
    else if (b2 < 8320) { b2 -= 6400; W = Wc; WT = dqc + (size_t)D * D; K = D; N = L; }
    else if (b2 < 10240) { b2 -= 8320; W = Wk; WT = dkv; K = L; N = D; }
    else { b2 -= 10240; W = Wv; WT = dkv + (size_t)D * L; K = L; N = D; }
    int nx = N / 64;
    int n0 = (b2 % nx) * 64, k0 = (b2 / nx) * 64;

    __shared__ unsigned short tile[64][65];  // [k][n], odd pad
    int c4 = (t & 15) * 4, r16 = t >> 4;
#pragma unroll
    for (int it = 0; it < 4; ++it) {
        int r = r16 + it * 16;
        float4 f = *(const float4*)&W[(size_t)(k0 + r) * N + n0 + c4];
        tile[r][c4 + 0] = cvt_bf(f.x);
        tile[r][c4 + 1] = cvt_bf(f.y);
        tile[r][c4 + 2] = cvt_bf(f.z);
        tile[r][c4 + 3] = cvt_bf(f.w);
    }
    __syncthreads();
    int n = t >> 2, kc = (t & 3) * 16;
    unsigned short o[16];
#pragma unroll
    for (int j = 0; j < 16; ++j) o[j] = tile[kc + j][n];
    unsigned short* dst = &WT[(size_t)(n0 + n) * K + k0 + kc];
    *(uint4*)dst = *(const uint4*)o;
    *(uint4*)(dst + 8) = *(const uint4*)(o + 8);
}

// ================= 256x256 pipelined bf16 GEMM (control, unchanged) ======
#define STAGE_A(S, H, KT)                                                              \
    do {                                                                               \
        GLDS16(aS[H][0] + (size_t)(KT) * 64, &Abuf[S][(H) * 8192 + wid * 512]);        \
        GLDS16(aS[H][1] + (size_t)(KT) * 64, &Abuf[S][(H) * 8192 + 4096 + wid * 512]); \
    } while (0)
#define STAGE_B(S, H, KT)                                                              \
    do {                                                                               \
        GLDS16(bS[H][0] + (size_t)(KT) * 64, &Bbuf[S][(H) * 8192 + wid * 512]);        \
        GLDS16(bS[H][1] + (size_t)(KT) * 64, &Bbuf[S][(H) * 8192 + 4096 + wid * 512]); \
    } while (0)

#define LDA_HALF(S, QM)                                                                   \
    do {                                                                                  \
        _Pragma("unroll") for (int mi = 0; mi < 4; ++mi)                                  \
            _Pragma("unroll") for (int kh = 0; kh < 2; ++kh)                              \
                af[mi][kh] =                                                              \
                    *(const bf16x8*)&Abuf[S][((QM) * 8192 + aoff + mi * 1024) ^ (kh * 32)]; \
    } while (0)
#define LDB_HALF(S, QN, BF)                                                               \
    do {                                                                                  \
        _Pragma("unroll") for (int ni = 0; ni < 2; ++ni)                                  \
            _Pragma("unroll") for (int kh = 0; kh < 2; ++kh)                              \
                BF[ni][kh] =                                                              \
                    *(const bf16x8*)&Bbuf[S][((QN) * 8192 + boff + ni * 1024) ^ (kh * 32)]; \
    } while (0)

#define MMAQ(QM, QN, BF)                                                                \
    do {                                                                                \
        _Pragma("unroll") for (int mi = 0; mi < 4; ++mi)                                \
            _Pragma("unroll") for (int ni = 0; ni < 2; ++ni)                            \
                _Pragma("unroll") for (int kh = 0; kh < 2; ++kh)                        \
                    acc[(QM) * 4 + mi][(QN) * 2 + ni] =                                 \
                        MFMA16(af[mi][kh], BF[ni][kh], acc[(QM) * 4 + mi][(QN) * 2 + ni]); \
    } while (0)

#define KTILE_V2(S, T, STG1, STG2, VMOP, RDNEXT)       \
    {                                                  \
        const int s_ = (S);                            \
        LDB_HALF(s_, 1, bf1);                          \
        STG1(STAGE_B(s_ ^ 1, 0, (T) + 1);)             \
        __builtin_amdgcn_s_setprio(1);                 \
        MMAQ(0, 0, bf0);                               \
        __builtin_amdgcn_s_setprio(0);                 \
        WAIT_LGKM0();                                  \
        BARRIER();                                     \
        STG2(STAGE_A(s_, 0, (T) + 2);                  \
             STAGE_B(s_, 1, (T) + 2);)                 \
        __builtin_amdgcn_s_setprio(1);                 \
        MMAQ(0, 1, bf1);                               \
        __builtin_amdgcn_s_setprio(0);                 \
        LDA_HALF(s_, 1);                               \
        __builtin_amdgcn_s_setprio(1);                 \
        MMAQ(1, 1, bf1);                               \
        __builtin_amdgcn_s_setprio(0);                 \
        WAIT_LGKM0();                                  \
        BARRIER();                                     \
        STG2(STAGE_A(s_, 1, (T) + 2);)                 \
        __builtin_amdgcn_s_setprio(1);                 \
        MMAQ(1, 0, bf0);                               \
        __builtin_amdgcn_s_setprio(0);                 \
        VMOP;                                          \
        BARRIER();                                     \
        RDNEXT(LDA_HALF(s_ ^ 1, 0); LDB_HALF(s_ ^ 1, 0, bf0);) \
    }

__global__ __launch_bounds__(512, 2) void gemm256(const unsigned short* __restrict__ A, int lda,
                                                  const unsigned short* __restrict__ BT, int ldb,
                                                  const float* __restrict__ bias0,
                                                  const float* __restrict__ bias1, int nsplit,
                                                  unsigned short* __restrict__ C, int ldc,
                                                  int K, float s0, float s1, int gx) {
    __shared__ __align__(16) unsigned short Abuf[2][16384];  // 2 x 32KB
    __shared__ __align__(16) unsigned short Bbuf[2][16384];

    int nwg = gridDim.x, orig = blockIdx.x;
    int cpx = nwg >> 3;
    int wgid = (orig & 7) * cpx + (orig >> 3);
    int tm = wgid / gx, tn = wgid % gx;
    int m0 = tm * 256, n0 = tn * 256;

    int tid = threadIdx.x, lane = tid & 63, wid = tid >> 6;
    int wm = wid >> 2, wn = wid & 3;
    int lrow = lane & 15, lkg = lane >> 4;

    int t5 = tid >> 3;
    int cole = ((tid & 7) ^ ((tid >> 3) & 7)) << 3;
    const unsigned short* aS[2][2];
    const unsigned short* bS[2][2];
#pragma unroll
    for (int H = 0; H < 2; ++H)
#pragma unroll
        for (int c = 0; c < 2; ++c) {
            int rA = (c << 7) | (H << 6) | t5;
            int rB = (((c << 1) | (t5 >> 5)) << 6) | (H << 5) | (t5 & 31);
            aS[H][c] = A + (size_t)(m0 + rA) * lda + cole;
            bS[H][c] = BT + (size_t)(n0 + rB) * ldb + cole;
        }

    int xorc = (lkg * 8) ^ ((lrow & 7) << 3);
    int aoff = wm * 4096 + lrow * 64 + xorc;
    int boff = wn * 2048 + lrow * 64 + xorc;

    f32x4 acc[8][4];
#pragma unroll
    for (int i = 0; i < 8; ++i)
#pragma unroll
        for (int j = 0; j < 4; ++j) acc[i][j] = (f32x4){0.f, 0.f, 0.f, 0.f};
    bf16x8 af[4][2], bf0[2][2], bf1[2][2];

    const int nkt = K >> 6;

    STAGE_A(0, 0, 0); STAGE_A(0, 1, 0); STAGE_B(0, 0, 0); STAGE_B(0, 1, 0);
    STAGE_A(1, 0, 1); STAGE_B(1, 1, 1); STAGE_A(1, 1, 1);
    VM6;
    BARRIER();
    LDA_HALF(0, 0);
    LDB_HALF(0, 0, bf0);

    int t = 0;
    for (; t + 2 < nkt; ++t) KTILE_V2(t & 1, t, KEEP, KEEP, VM6, KEEP);
    KTILE_V2(t & 1, t, KEEP, DROP, VM0, KEEP);
    ++t;
    KTILE_V2(t & 1, t, DROP, DROP, VMNONE, DROP);

#pragma unroll
    for (int ni = 0; ni < 4; ++ni) {
        int col = n0 + wn * 64 + ni * 16 + lrow;
        float bval = (col < nsplit) ? bias0[col] : bias1[col - nsplit];
        float scl = (col < nsplit) ? s0 : s1;
#pragma unroll
        for (int mi = 0; mi < 8; ++mi) {
            int row = m0 + wm * 128 + mi * 16 + lkg * 4;
#pragma unroll
            for (int j = 0; j < 4; ++j)
                C[(size_t)(row + j) * ldc + col] = cvt_bf((acc[mi][ni][j] + bval) * scl);
        }
    }
}

// ================= 128x128 bf16 GEMM, now 4 blocks/CU =================
#define STG128(S, KT)                                                                  \
    do {                                                                               \
        _Pragma("unroll") for (int i_ = 0; i_ < 4; ++i_)                               \
            GLDS16(Ag + (size_t)(i_ * 32) * lda + (size_t)(KT) * 64,                   \
                   &Abuf[S][i_ * 2048 + wid * 512]);                                   \
        _Pragma("unroll") for (int i_ = 0; i_ < 4; ++i_)                               \
            GLDS16(Bg + (size_t)(i_ * 32) * ldb + (size_t)(KT) * 64,                   \
                   &Bbuf[S][i_ * 2048 + wid * 512]);                                   \
    } while (0)

__global__ __launch_bounds__(256, 4) void gemm128(const unsigned short* __restrict__ A, int lda,
                                                  const unsigned short* __restrict__ BT, int ldb,
                                                  const float* __restrict__ bias0,
                                                  const float* __restrict__ bias1, int nsplit,
                                                  unsigned short* __restrict__ C, int ldc,
                                                  int K, float s0, float s1, int gy) {
    __shared__ __align__(16) unsigned short Abuf[2][8192];  // 2 x 16KB
    __shared__ __align__(16) unsigned short Bbuf[2][8192];

    int b = blockIdx.x;
    int tm = b % gy, tn = b / gy;
    int m0 = tm * 128, n0 = tn * 128;
    int tid = threadIdx.x, lane = tid & 63, wid = tid >> 6;
    int wm = wid >> 1, wn = wid & 1;
    int lrow = lane & 15, lkg = lane >> 4;

    int srow = tid >> 3;
    int cole = ((tid & 7) ^ ((tid >> 3) & 7)) << 3;
    const unsigned short* Ag = A + (size_t)(m0 + srow) * lda + cole;
    const unsigned short* Bg = BT + (size_t)(n0 + srow) * ldb + cole;

    int xorc8 = (lrow & 7) << 3;
    int aoff = (wm * 64 + lrow) * 64;
    int boff = (wn * 64 + lrow) * 64;

    f32x4 acc[4][4];
#pragma unroll
    for (int i = 0; i < 4; ++i)
#pragma unroll
        for (int j = 0; j < 4; ++j) acc[i][j] = (f32x4){0.f, 0.f, 0.f, 0.f};

    const int nkt = K >> 6;
    STG128(0, 0);
    for (int t = 0; t < nkt; ++t) {
        const int cur = t & 1;
        if (t + 1 < nkt) {
            STG128(cur ^ 1, t + 1);
            VM8;
        } else {
            VM0;
        }
        BARRIER();
        bf16x8 af[4][2], bv[4][2];
#pragma unroll
        for (int mi = 0; mi < 4; ++mi)
#pragma unroll
            for (int kh = 0; kh < 2; ++kh)
                af[mi][kh] = *(const bf16x8*)&Abuf[cur][aoff + mi * 1024 + (((kh * 4 + lkg) << 3) ^ xorc8)];
#pragma unroll
        for (int ni = 0; ni < 4; ++ni)
#pragma unroll
            for (int kh = 0; kh < 2; ++kh)
                bv[ni][kh] = *(const bf16x8*)&Bbuf[cur][boff + ni * 1024 + (((kh * 4 + lkg) << 3) ^ xorc8)];
        __builtin_amdgcn_s_setprio(1);
#pragma unroll
        for (int mi = 0; mi < 4; ++mi)
#pragma unroll
            for (int ni = 0; ni < 4; ++ni)
#pragma unroll
                for (int kh = 0; kh < 2; ++kh)
                    acc[mi][ni] = MFMA16(af[mi][kh], bv[ni][kh], acc[mi][ni]);
        __builtin_amdgcn_s_setprio(0);
        BARRIER();
    }

#pragma unroll
    for (int ni = 0; ni < 4; ++ni) {
        int col = n0 + wn * 64 + ni * 16 + lrow;
        float bval = (col < nsplit) ? bias0[col] : bias1[col - nsplit];
        float scl = (col < nsplit) ? s0 : s1;
#pragma unroll
        for (int mi = 0; mi < 4; ++mi) {
            int row = m0 + wm * 64 + mi * 16 + lkg * 4;
#pragma unroll
            for (int j = 0; j < 4; ++j)
                C[(size_t)(row + j) * ldc + col] = cvt_bf((acc[mi][ni][j] + bval) * scl);
        }
    }
}

// ---------------- flash attention (pipelined staging + setprio + defer-max) ----------
__global__ __launch_bounds__(256) void attn(const unsigned short* __restrict__ q, int ldq,
                                            const unsigned short* __restrict__ k, int ldk,
                                            const unsigned short* __restrict__ v, int ldv,
                                            float* __restrict__ out) {
    const int S = 1024, D = 5120, Dh = 40;
    int b = blockIdx.z, h = blockIdx.y, qt = blockIdx.x;
    int t = threadIdx.x, lane = t & 63, wid = t >> 6;
    int lrow = lane & 15, lkg = lane >> 4;

    __shared__ __align__(16) unsigned short Ks[64 * 72];
    __shared__ __align__(16) unsigned short Vs[64 * 72];
    __shared__ __align__(16) unsigned short Ps[4][16 * 72];

    const size_t qbase = ((size_t)b * S) * ldq + (size_t)h * Dh;
    int q0 = qt * 64 + wid * 16;

    bf16x8 qf0, qf1;
    {
        const unsigned short* qp = q + qbase + (size_t)(q0 + lrow) * ldq;
        qf0 = *(const bf16x8*)(qp + lkg * 8);
        qf1 = (lkg == 0) ? *(const bf16x8*)(qp + 32) : bf8_zero();
    }

    int rrK = t >> 3, ccK = t & 7;
    int rrV = t & 63, ccV = t >> 6;
    const unsigned short* kp = k + ((size_t)b * S) * ldk + (size_t)h * Dh +
                               (size_t)rrK * ldk + ccK * 8;
    const unsigned short* vp = v + ((size_t)b * S) * ldv + (size_t)h * Dh +
                               (size_t)rrV * ldv + ccV * 8;
    const size_t kstep = (size_t)64 * ldk, vstep = (size_t)64 * ldv;

    uint4 kv0, kv1, vv0, vv1;
    kv0 = kv1 = vv0 = vv1 = make_uint4(0, 0, 0, 0);
    if (ccK < 5) { kv0 = *(const uint4*)kp; kv1 = *(const uint4*)(kp + 32 * ldk); }
    vv0 = *(const uint4*)vp;
    if (ccV == 0) vv1 = *(const uint4*)(vp + 32);
    kp += kstep; vp += vstep;

    f32x4 acc[3];
#pragma unroll
    for (int nb = 0; nb < 3; ++nb) acc[nb] = (f32x4){0.f, 0.f, 0.f, 0.f};
    float mrun = -INFINITY, lrun = 0.f;

    for (int kt = 0; kt < 16; ++kt) {
        __syncthreads();
        uint4 w0 = (ccK < 5) ? kv0 : make_uint4(0, 0, 0, 0);
        uint4 w1 = (ccK < 5) ? kv1 : make_uint4(0, 0, 0, 0);
        *(uint4*)&Ks[rrK * 72 + ccK * 8] = w0;
        *(uint4*)&Ks[(rrK + 32) * 72 + ccK * 8] = w1;
        {
            const unsigned short* pv = (const unsigned short*)&vv0;
#pragma unroll
            for (int j = 0; j < 8; ++j) Vs[(ccV * 8 + j) * 72 + rrV] = pv[j];
            if (ccV < 2) {
                uint4 z = (ccV == 0) ? vv1 : make_uint4(0, 0, 0, 0);
                const unsigned short* pz = (const unsigned short*)&z;
#pragma unroll
                for (int j = 0; j < 8; ++j) Vs[((ccV + 4) * 8 + j) * 72 + rrV] = pz[j];
            }
        }
        __syncthreads();
        if (kt + 1 < 16) {
            if (ccK < 5) { kv0 = *(const uint4*)kp; kv1 = *(const uint4*)(kp + 32 * ldk); }
            vv0 = *(const uint4*)vp;
            if (ccV == 0) vv1 = *(const uint4*)(vp + 32);
            kp += kstep; vp += vstep;
        }

        f32x4 sf[4];
        __builtin_amdgcn_s_setprio(1);
#pragma unroll
        for (int nb = 0; nb < 4; ++nb) {
            sf[nb] = (f32x4){0.f, 0.f, 0.f, 0.f};
            bf16x8 kf0 = *(const bf16x8*)&Ks[(nb * 16 + lrow) * 72 + lkg * 8];
            bf16x8 kf1 = *(const bf16x8*)&Ks[(nb * 16 + lrow) * 72 + 32 + lkg * 8];
            sf[nb] = MFMA16(kf0, qf0, sf[nb]);
            sf[nb] = MFMA16(kf1, qf1, sf[nb]);
        }
        __builtin_amdgcn_s_setprio(0);

        float tm = sf[0][0];
#pragma unroll
        for (int nb = 0; nb < 4; ++nb)
#pragma unroll
            for (int i = 0; i < 4; ++i) tm = fmaxf(tm, sf[nb][i]);
        tm = fmaxf(tm, __shfl_xor(tm, 16));
        tm = fmaxf(tm, __shfl_xor(tm, 32));

        float mn = mrun, al = 1.0f;
        bool resc = !__all(tm <= mrun + 11.0f);
        if (resc) {
            mn = fmaxf(mrun, tm);
            al = EXP2F(mrun - mn);
            mrun = mn;
        }
        float rs = 0.f;
#pragma unroll
        for (int nb = 0; nb < 4; ++nb) {
            bf16x4 pk;
#pragma unroll
            for (int i = 0; i < 4; ++i) {
                float p = EXP2F(sf[nb][i] - mn);
                rs += p;
                pk[i] = (__bf16)p;
            }
            *(bf16x4*)&Ps[wid][lrow * 72 + nb * 16 + lkg * 4] = pk;
        }
        rs += __shfl_xor(rs, 16);
        rs += __shfl_xor(rs, 32);
        lrun = lrun * al + rs;

        if (resc) {
            float alr[4];
#pragma unroll
            for (int i = 0; i < 4; ++i) alr[i] = __shfl(al, lkg * 4 + i);
#pragma unroll
            for (int nb = 0; nb < 3; ++nb)
#pragma unroll
                for (int i = 0; i < 4; ++i) acc[nb][i] *= alr[i];
        }

        __builtin_amdgcn_s_setprio(1);
#pragma unroll
        for (int kk = 0; kk < 2; ++kk) {
            bf16x8 pf = *(const bf16x8*)&Ps[wid][lrow * 72 + kk * 32 + lkg * 8];
#pragma unroll
            for (int nb = 0; nb < 3; ++nb) {
                bf16x8 vf = *(const bf16x8*)&Vs[(nb * 16 + lrow) * 72 + kk * 32 + lkg * 8];
                acc[nb] = MFMA16(pf, vf, acc[nb]);
            }
        }
        __builtin_amdgcn_s_setprio(0);
    }

    float lr[4];
#pragma unroll
    for (int i = 0; i < 4; ++i) lr[i] = __shfl(lrun, lkg * 4 + i);
#pragma unroll
    for (int i = 0; i < 4; ++i) {
        float inv = 1.0f / lr[i];
        int s = q0 + lkg * 4 + i;
#pragma unroll
        for (int nb = 0; nb < 3; ++nb) {
            int d = nb * 16 + lrow;
            if (d < Dh) out[((size_t)(b * S + s)) * D + h * Dh + d] = acc[nb][i] * inv;
        }
    }
}

extern "C" void kernel_launch(void* const* d_in, const int* in_sizes, int n_in,
                              void* d_out, int out_size, void* d_ws, size_t ws_size,
                              hipStream_t stream) {
    const int M = 2048, D = 5120, L = 1536, NQ = D + L /*6656*/, NKV = 2 * D /*10240*/;
    const float* x  = (const float*)d_in[0];
    const float* Wq = (const float*)d_in[1];
    const float* bq = (const float*)d_in[2];
    const float* Wc = (const float*)d_in[3];
    const float* bc = (const float*)d_in[4];
    const float* Wk = (const float*)d_in[5];
    const float* bk = (const float*)d_in[6];
    const float* Wv = (const float*)d_in[7];
    const float* bv = (const float*)d_in[8];
    float* out = (float*)d_out;

    unsigned short* ws = (unsigned short*)d_ws;
    size_t off = 0;
    unsigned short* xb    = ws + off; off += (size_t)M * D;
    unsigned short* WqcT  = ws + off; off += (size_t)NQ * D;   // [Wq|Wc]^T : [6656][5120]
    unsigned short* WkvT  = ws + off; off += (size_t)NKV * L;  // [Wk|Wv]^T : [10240][1536]
    unsigned short* qkvb  = ws + off; off += (size_t)M * NQ;   // [q | kv_latent]
    unsigned short* kvout = ws + off; off += (size_t)M * NKV;  // [k | v]

    // prep: 5120 (x) + 6400 (Wq) + 1920 (Wc) + 1920 (Wk) + 1920 (Wv) = 17280 blocks
    prep<<<17280, 256, 0, stream>>>(x, Wq, Wc, Wk, Wv, xb, WqcT, WkvT);

    const float qscale = 1.4426950408889634f / 6.324555320336759f;  // log2(e)/sqrt(40)

    // GEMM1: [q | kv_latent] = x @ [Wq | Wc]   grid 208 (8x26), 256^2 pipelined
    gemm256<<<dim3((NQ / 256) * (M / 256)), 512, 0, stream>>>(xb, D, WqcT, D, bq, bc, D,
                                                              qkvb, NQ, D, qscale, 1.0f,
                                                              NQ / 256);
    // GEMM2: [k | v] = kv_latent @ [Wk | Wv]   grid 1280 (80x16), 128^2 4 blocks/CU
    gemm128<<<dim3((NKV / 128) * (M / 128)), 256, 0, stream>>>(qkvb + D, NQ, WkvT, L, bk, bv, D,
                                                               kvout, NKV, L, 1.0f, 1.0f,
                                                               M / 128);

    attn<<<dim3(1024 / 64, 128, 2), 256, 0, stream>>>(qkvb, NQ, kvout, NKV, kvout + D, NKV, out);
}